// Round 5
// baseline (8655.335 us; speedup 1.0000x reference)
//
#include <hip/hip_runtime.h>
#include <utility>

#define HID 256

typedef __attribute__((ext_vector_type(8))) short bf16x8;
typedef __attribute__((ext_vector_type(4))) float f32x4;
typedef __attribute__((ext_vector_type(4))) unsigned short us4;

// Topology constants for GRID_N=80
constexpr size_t MAXN3 = 100489;
constexpr size_t MAXE3 = 300200;

// Transposed-weight scratch offsets (elements). Layout per matrix: [256 n][K k].
constexpr size_t OFF_IN1 = 0;                       // 2 mats K=128
constexpr size_t OFF_IN2 = OFF_IN1 + 2 * 256 * 128; // 2 mats K=384
constexpr size_t OFF_IN3 = OFF_IN2 + 2 * 256 * 384;
constexpr size_t OFF_H1  = OFF_IN3 + 2 * 256 * 384; // 24 mats K=256
constexpr size_t OFF_H2  = OFF_H1 + 24 * 256 * 256;
constexpr size_t OFF_H3  = OFF_H2 + 24 * 256 * 256;
constexpr size_t WT_TOTAL = OFF_H3 + 24 * 256 * 256;

// Static device scratch (BSS — graph-capture safe).
__device__ float g_A [MAXN3 * 256];
__device__ float g_B [MAXN3 * 256];
__device__ float g_Hb[MAXN3 * 256];
__device__ float g_D [MAXN3 * 256];
__device__ float g_VA[MAXN3 * 128];
__device__ float g_C0[MAXN3 * 3];
__device__ float g_C2[MAXN3 * 3];
__device__ float g_Vv[MAXN3 * 3];
__device__ float g_T [56 * 56 * 128];
__device__ unsigned short g_Wth[WT_TOTAL];
__device__ unsigned short g_Wtl[WT_TOTAL];
// CSR scratch
__device__ int g_deg   [MAXN3];
__device__ int g_rowptr[MAXN3 + 1];
__device__ int g_cursor[MAXN3];
__device__ int g_adj   [2 * MAXE3];

// ---------------- weight transpose + bf16 hi/lo split ----------------
__global__ __launch_bounds__(256) void k_wtrans(const float* __restrict__ W,
                                                unsigned short* __restrict__ Oh,
                                                unsigned short* __restrict__ Ol,
                                                int K) {
  __shared__ float t[32][33];
  int mat = blockIdx.z;
  const float* Wm = W + (size_t)mat * K * 256;
  unsigned short* OhM = Oh + (size_t)mat * K * 256;
  unsigned short* OlM = Ol + (size_t)mat * K * 256;
  int x = threadIdx.x;
  int y = threadIdx.y;
  int k0 = blockIdx.x * 32, n0 = blockIdx.y * 32;
#pragma unroll
  for (int i = 0; i < 4; ++i) {
    int kk = y + i * 8;
    t[kk][x] = Wm[(size_t)(k0 + kk) * 256 + n0 + x];
  }
  __syncthreads();
#pragma unroll
  for (int i = 0; i < 4; ++i) {
    int nn = y + i * 8;
    float v = t[x][nn];
    unsigned u = __float_as_uint(v);
    unsigned short hi = (unsigned short)(u >> 16);
    float hv = __uint_as_float((unsigned)hi << 16);
    unsigned short lo = (unsigned short)(__float_as_uint(v - hv) >> 16);
    OhM[(size_t)(n0 + nn) * K + k0 + x] = hi;
    OlM[(size_t)(n0 + nn) * K + k0 + x] = lo;
  }
}

// ---------------- CSR build ----------------

__global__ __launch_bounds__(256) void k_count(const int* __restrict__ edges,
                                               int* __restrict__ deg, int E) {
  int e = blockIdx.x * blockDim.x + threadIdx.x;
  if (e >= E) return;
  atomicAdd(&deg[edges[2 * e + 0]], 1);
  atomicAdd(&deg[edges[2 * e + 1]], 1);
}

__global__ __launch_bounds__(1024) void k_scan(const int* __restrict__ deg,
                                               int* __restrict__ rowptr,
                                               int* __restrict__ cursor, int N) {
  __shared__ int sums[1024];
  int t = threadIdx.x;
  int chunk = (N + 1023) / 1024;
  int lo = t * chunk;
  int hi = min(lo + chunk, N);
  int s = 0;
  for (int i = lo; i < hi; ++i) s += deg[i];
  sums[t] = s;
  __syncthreads();
  for (int off = 1; off < 1024; off <<= 1) {
    int v = (t >= off) ? sums[t - off] : 0;
    __syncthreads();
    sums[t] += v;
    __syncthreads();
  }
  int base = (t == 0) ? 0 : sums[t - 1];
  for (int i = lo; i < hi; ++i) {
    rowptr[i] = base;
    cursor[i] = base;
    base += deg[i];
  }
  if (t == 1023) rowptr[N] = sums[1023];
}

__global__ __launch_bounds__(256) void k_fill(const int* __restrict__ edges,
                                              int* __restrict__ cursor,
                                              int* __restrict__ adj, int E) {
  int e = blockIdx.x * blockDim.x + threadIdx.x;
  if (e >= E) return;
  int a = edges[2 * e + 0];
  int b = edges[2 * e + 1];
  adj[atomicAdd(&cursor[a], 1)] = b;
  adj[atomicAdd(&cursor[b], 1)] = a;
}

// ---------------- misc kernels ----------------

__global__ __launch_bounds__(128) void k_transpose(const float* __restrict__ in,
                                                   float* __restrict__ out, int HW) {
  int p = blockIdx.x;
  int c = threadIdx.x;
  if (p < HW) out[(size_t)p * 128 + c] = in[(size_t)c * HW + p];
}

__global__ __launch_bounds__(128) void k_vert_align(const float* __restrict__ fT,
                                                    const float* __restrict__ verts,
                                                    float* __restrict__ out,
                                                    int N, int H, int W) {
  int v = blockIdx.x;
  if (v >= N) return;
  int c = threadIdx.x;
  float vx = verts[(size_t)v * 3 + 0];
  float vy = verts[(size_t)v * 3 + 1];
  float fx = (vx + 1.f) * 0.5f * (float)(W - 1);
  float fy = (vy + 1.f) * 0.5f * (float)(H - 1);
  float x0f = floorf(fx), y0f = floorf(fy);
  float wx = fx - x0f, wy = fy - y0f;
  int x0 = (int)x0f, y0 = (int)y0f;
  float acc = 0.f;
#pragma unroll
  for (int dy = 0; dy < 2; ++dy) {
#pragma unroll
    for (int dx = 0; dx < 2; ++dx) {
      int yi = y0 + dy, xi = x0 + dx;
      bool valid = (yi >= 0) && (yi < H) && (xi >= 0) && (xi < W);
      int yc = min(max(yi, 0), H - 1);
      int xc = min(max(xi, 0), W - 1);
      float val = fT[((size_t)yc * W + xc) * 128 + c];
      float wgt = (dy ? wy : 1.f - wy) * (dx ? wx : 1.f - wx);
      acc += valid ? val * wgt : 0.f;
    }
  }
  out[(size_t)v * 128 + c] = acc;
}

// ---------------- full-width MFMA split-bf16 dual matmul ----------------
// Tile: 64 rows x 256 cols, both W0 and W1. Grid = ceil(N/64) blocks.
// GATHER: staging computes X[v] + sum_{u in adj(v)} Hp[u] on the fly.
#define SWZ(row, slot) (((row) * 64) + (((slot) ^ ((row) & 7)) * 8))

template <bool ACC, bool GATHER>
__global__ __launch_bounds__(256, 2) void k_mfma_full(
    const float* __restrict__ X, const float* __restrict__ Hp,
    const int* __restrict__ rowptr, const int* __restrict__ adj,
    int ldX, int Kmm,
    const unsigned short* __restrict__ w0h, const unsigned short* __restrict__ w0l,
    const unsigned short* __restrict__ w1h, const unsigned short* __restrict__ w1l,
    int ldW,
    const float* __restrict__ b0, const float* __restrict__ b1,
    float* __restrict__ Y0, float* __restrict__ Y1, int N) {
  __shared__ unsigned short lds[6][64 * 64]; // xhi,xlo + per-cb w0h,w0l,w1h,w1l
  int tid = threadIdx.x;
  int lane = tid & 63;
  int wid = tid >> 6;
  int wm = wid & 1, wn = wid >> 1;
  int row0 = blockIdx.x * 64;

  f32x4 acc[4][2][2][2]; // [cb][w][m][n]
#pragma unroll
  for (int cb = 0; cb < 4; ++cb)
#pragma unroll
    for (int w = 0; w < 2; ++w)
#pragma unroll
      for (int m = 0; m < 2; ++m)
#pragma unroll
        for (int n = 0; n < 2; ++n) acc[cb][w][m][n] = (f32x4){0.f, 0.f, 0.f, 0.f};

  const unsigned short* wsrc[4] = {w0h, w0l, w1h, w1l};

  for (int kt = 0; kt < Kmm; kt += 64) {
    // ---- stage X tile (f32 -> bf16 hi/lo, swizzled; optional fused gather) ----
#pragma unroll
    for (int it = 0; it < 4; ++it) {
      int linear = tid + it * 256;
      int row = linear >> 4;
      int c4 = (linear & 15) * 4;
      int v = row0 + row;
      float4 xv = make_float4(0.f, 0.f, 0.f, 0.f);
      if (v < N) {
        xv = *(const float4*)(X + (size_t)v * ldX + kt + c4);
        if (GATHER) {
          int lo = rowptr[v], hi = rowptr[v + 1];
          for (int i = lo; i < hi; ++i) {
            float4 h = *(const float4*)(Hp + (size_t)adj[i] * HID + kt + c4);
            xv.x += h.x; xv.y += h.y; xv.z += h.z; xv.w += h.w;
          }
        }
      }
      us4 hv, lv;
#pragma unroll
      for (int j = 0; j < 4; ++j) {
        float v2 = (&xv.x)[j];
        unsigned u = __float_as_uint(v2);
        unsigned short hi16 = (unsigned short)(u >> 16);
        float hf = __uint_as_float((unsigned)hi16 << 16);
        unsigned short lo16 = (unsigned short)(__float_as_uint(v2 - hf) >> 16);
        hv[j] = hi16;
        lv[j] = lo16;
      }
      int s = c4 >> 3, half = (c4 >> 2) & 1;
      int off = SWZ(row, s) + half * 4;
      *(us4*)&lds[0][off] = hv;
      *(us4*)&lds[1][off] = lv;
    }
    // ---- per 64-col group: stage W, compute ----
#pragma unroll
    for (int cb = 0; cb < 4; ++cb) {
#pragma unroll
      for (int a = 0; a < 4; ++a) {
        const unsigned short* src = wsrc[a];
#pragma unroll
        for (int it = 0; it < 2; ++it) {
          int linear = tid + it * 256;
          int n = linear >> 3;
          int slot = linear & 7;
          uint4 v = *(const uint4*)(src + (size_t)(cb * 64 + n) * ldW + kt + slot * 8);
          *(uint4*)&lds[2 + a][SWZ(n, slot)] = v;
        }
      }
      __syncthreads();
#pragma unroll
      for (int ks = 0; ks < 2; ++ks) {
        int slot = ks * 4 + (lane >> 4);
        bf16x8 ah[2], al[2];
#pragma unroll
        for (int m = 0; m < 2; ++m) {
          int row = wm * 32 + m * 16 + (lane & 15);
          ah[m] = *(const bf16x8*)&lds[0][SWZ(row, slot)];
          al[m] = *(const bf16x8*)&lds[1][SWZ(row, slot)];
        }
        bf16x8 bh[2][2], bl[2][2];
#pragma unroll
        for (int w = 0; w < 2; ++w)
#pragma unroll
          for (int n = 0; n < 2; ++n) {
            int nr = wn * 32 + n * 16 + (lane & 15);
            bh[w][n] = *(const bf16x8*)&lds[2 + 2 * w][SWZ(nr, slot)];
            bl[w][n] = *(const bf16x8*)&lds[3 + 2 * w][SWZ(nr, slot)];
          }
#pragma unroll
        for (int w = 0; w < 2; ++w)
#pragma unroll
          for (int m = 0; m < 2; ++m)
#pragma unroll
            for (int n = 0; n < 2; ++n) {
              f32x4 c = acc[cb][w][m][n];
              c = __builtin_amdgcn_mfma_f32_16x16x32_bf16(al[m], bh[w][n], c, 0, 0, 0);
              c = __builtin_amdgcn_mfma_f32_16x16x32_bf16(ah[m], bl[w][n], c, 0, 0, 0);
              c = __builtin_amdgcn_mfma_f32_16x16x32_bf16(ah[m], bh[w][n], c, 0, 0, 0);
              acc[cb][w][m][n] = c;
            }
      }
      __syncthreads();
    }
  }

  // ---- epilogue ----
#pragma unroll
  for (int cb = 0; cb < 4; ++cb)
#pragma unroll
    for (int w = 0; w < 2; ++w) {
      float* Yp = w ? Y1 : Y0;
      const float* bp = w ? b1 : b0;
#pragma unroll
      for (int m = 0; m < 2; ++m)
#pragma unroll
        for (int n = 0; n < 2; ++n) {
          int col = cb * 64 + wn * 32 + n * 16 + (lane & 15);
          int rbase = row0 + wm * 32 + m * 16 + (lane >> 4) * 4;
          f32x4 v = acc[cb][w][m][n];
#pragma unroll
          for (int r = 0; r < 4; ++r) {
            int row = rbase + r;
            if (row < N) {
              if (ACC)
                Yp[(size_t)row * HID + col] += v[r];
              else
                Yp[(size_t)row * HID + col] = v[r] + bp[col];
            }
          }
        }
    }
}

// OUT[v] = Y[v] + sum_{u in adj(v)} H[u]
__global__ __launch_bounds__(256) void k_gather_out(const int* __restrict__ rowptr,
                                                    const int* __restrict__ adj,
                                                    const float* __restrict__ Y,
                                                    const float* __restrict__ H,
                                                    float* __restrict__ OUT, int N) {
  int idx = blockIdx.x * blockDim.x + threadIdx.x;
  int v = idx >> 6;
  if (v >= N) return;
  int c = (threadIdx.x & 63) * 4;
  float4 acc = *(const float4*)(Y + (size_t)v * HID + c);
  int lo = rowptr[v], hi = rowptr[v + 1];
  for (int i = lo; i < hi; ++i) {
    float4 h = *(const float4*)(H + (size_t)adj[i] * HID + c);
    acc.x += h.x; acc.y += h.y; acc.z += h.z; acc.w += h.w;
  }
  *(float4*)(OUT + (size_t)v * HID + c) = acc;
}

__global__ __launch_bounds__(256) void k_rowdot3(const float* __restrict__ X,
                                                 const float* __restrict__ W,
                                                 const float* __restrict__ b,
                                                 float* __restrict__ Y, int N) {
  int gid = blockIdx.x * blockDim.x + threadIdx.x;
  int row = gid >> 6;
  int lane = threadIdx.x & 63;
  if (row >= N) return;
  float4 xv = ((const float4*)(X + (size_t)row * HID))[lane];
  float s0 = 0.f, s1 = 0.f, s2 = 0.f;
#pragma unroll
  for (int k = 0; k < 4; ++k) {
    float x = (&xv.x)[k];
    int kk = lane * 4 + k;
    s0 += x * W[kk * 3 + 0];
    s1 += x * W[kk * 3 + 1];
    s2 += x * W[kk * 3 + 2];
  }
#pragma unroll
  for (int off = 32; off > 0; off >>= 1) {
    s0 += __shfl_down(s0, off);
    s1 += __shfl_down(s1, off);
    s2 += __shfl_down(s2, off);
  }
  if (lane == 0) {
    Y[(size_t)row * 3 + 0] = s0 + b[0];
    Y[(size_t)row * 3 + 1] = s1 + b[1];
    Y[(size_t)row * 3 + 2] = s2 + b[2];
  }
}

__global__ __launch_bounds__(256) void k_scatter3(const int* __restrict__ edges,
                                                  const float* __restrict__ H,
                                                  float* __restrict__ OUT, int E) {
  int e = blockIdx.x * blockDim.x + threadIdx.x;
  if (e >= E) return;
  int a = edges[(size_t)e * 2 + 0];
  int b = edges[(size_t)e * 2 + 1];
#pragma unroll
  for (int k = 0; k < 3; ++k) {
    atomicAdd(&OUT[(size_t)a * 3 + k], H[(size_t)b * 3 + k]);
    atomicAdd(&OUT[(size_t)b * 3 + k], H[(size_t)a * 3 + k]);
  }
}

__global__ __launch_bounds__(256) void k_subdiv3(const float* __restrict__ c,
                                                 const int* __restrict__ edges,
                                                 float* __restrict__ v, int N, int E) {
  int i = blockIdx.x * blockDim.x + threadIdx.x;
  if (i >= N + E) return;
  if (i < N) {
#pragma unroll
    for (int k = 0; k < 3; ++k) v[(size_t)i * 3 + k] = c[(size_t)i * 3 + k];
  } else {
    int e = i - N;
    int a = edges[(size_t)e * 2 + 0];
    int b = edges[(size_t)e * 2 + 1];
#pragma unroll
    for (int k = 0; k < 3; ++k)
      v[(size_t)i * 3 + k] = 0.5f * (c[(size_t)a * 3 + k] + c[(size_t)b * 3 + k]);
  }
}

__global__ __launch_bounds__(256) void k_subdiv_feat(const float* __restrict__ x,
                                                     const int* __restrict__ edges,
                                                     float* __restrict__ out, int N, int E) {
  int idx = blockIdx.x * blockDim.x + threadIdx.x;
  int v = idx >> 6;
  if (v >= N + E) return;
  int c = (threadIdx.x & 63) * 4;
  float4 r;
  if (v < N) {
    r = *(const float4*)(x + (size_t)v * HID + c);
  } else {
    int e = v - N;
    int a = edges[(size_t)e * 2 + 0];
    int b = edges[(size_t)e * 2 + 1];
    float4 xa = *(const float4*)(x + (size_t)a * HID + c);
    float4 xb = *(const float4*)(x + (size_t)b * HID + c);
    r = make_float4(0.5f * (xa.x + xb.x), 0.5f * (xa.y + xb.y),
                    0.5f * (xa.z + xb.z), 0.5f * (xa.w + xb.w));
  }
  *(float4*)(out + (size_t)v * HID + c) = r;
}

// ---------------- launcher ----------------

extern "C" void kernel_launch(void* const* d_in, const int* in_sizes, int n_in,
                              void* d_out, int out_size, void* d_ws, size_t ws_size,
                              hipStream_t stream) {
  const float* conv64  = (const float*)d_in[0];
  const float* conv128 = (const float*)d_in[1];
  const float* conv256 = (const float*)d_in[2];
  const float* verts0  = (const float*)d_in[3];
  const int*   edges1  = (const int*)d_in[4];
  const int*   edges2  = (const int*)d_in[5];
  const int*   edges3  = (const int*)d_in[6];
  const float* w_in1 = (const float*)d_in[7],  *b_in1 = (const float*)d_in[8];
  const float* w_h1  = (const float*)d_in[9],  *b_h1  = (const float*)d_in[10];
  const float* w_out1= (const float*)d_in[11], *b_out1= (const float*)d_in[12];
  const float* w_in2 = (const float*)d_in[13], *b_in2 = (const float*)d_in[14];
  const float* w_h2  = (const float*)d_in[15], *b_h2  = (const float*)d_in[16];
  const float* w_out2= (const float*)d_in[17], *b_out2= (const float*)d_in[18];
  const float* w_in3 = (const float*)d_in[19], *b_in3 = (const float*)d_in[20];
  const float* w_h3  = (const float*)d_in[21], *b_h3  = (const float*)d_in[22];
  const float* w_out3= (const float*)d_in[23], *b_out3= (const float*)d_in[24];

  const int N1 = in_sizes[3] / 3;
  const int E1 = in_sizes[4] / 2;
  const int E2 = in_sizes[5] / 2;
  const int E3 = in_sizes[6] / 2;
  const int N2 = N1 + E1;
  const int N3 = N2 + E2;
  if ((size_t)N3 > MAXN3 || (size_t)E3 > MAXE3) return;

  float *A, *B, *Hb, *D, *VA, *C0, *C2, *Vv, *T;
  unsigned short *Wth, *Wtl;
  int *deg, *rowptr, *cursor, *adj;
  hipGetSymbolAddress((void**)&A,  HIP_SYMBOL(g_A));
  hipGetSymbolAddress((void**)&B,  HIP_SYMBOL(g_B));
  hipGetSymbolAddress((void**)&Hb, HIP_SYMBOL(g_Hb));
  hipGetSymbolAddress((void**)&D,  HIP_SYMBOL(g_D));
  hipGetSymbolAddress((void**)&VA, HIP_SYMBOL(g_VA));
  hipGetSymbolAddress((void**)&C0, HIP_SYMBOL(g_C0));
  hipGetSymbolAddress((void**)&C2, HIP_SYMBOL(g_C2));
  hipGetSymbolAddress((void**)&Vv, HIP_SYMBOL(g_Vv));
  hipGetSymbolAddress((void**)&T,  HIP_SYMBOL(g_T));
  hipGetSymbolAddress((void**)&Wth, HIP_SYMBOL(g_Wth));
  hipGetSymbolAddress((void**)&Wtl, HIP_SYMBOL(g_Wtl));
  hipGetSymbolAddress((void**)&deg,    HIP_SYMBOL(g_deg));
  hipGetSymbolAddress((void**)&rowptr, HIP_SYMBOL(g_rowptr));
  hipGetSymbolAddress((void**)&cursor, HIP_SYMBOL(g_cursor));
  hipGetSymbolAddress((void**)&adj,    HIP_SYMBOL(g_adj));

  // ---- weight transpose + split (once per launch, deterministic) ----
  k_wtrans<<<dim3(4, 8, 2),  dim3(32, 8), 0, stream>>>(w_in1, Wth + OFF_IN1, Wtl + OFF_IN1, 128);
  k_wtrans<<<dim3(12, 8, 2), dim3(32, 8), 0, stream>>>(w_in2, Wth + OFF_IN2, Wtl + OFF_IN2, 384);
  k_wtrans<<<dim3(12, 8, 2), dim3(32, 8), 0, stream>>>(w_in3, Wth + OFF_IN3, Wtl + OFF_IN3, 384);
  k_wtrans<<<dim3(8, 8, 24), dim3(32, 8), 0, stream>>>(w_h1,  Wth + OFF_H1,  Wtl + OFF_H1,  256);
  k_wtrans<<<dim3(8, 8, 24), dim3(32, 8), 0, stream>>>(w_h2,  Wth + OFF_H2,  Wtl + OFF_H2,  256);
  k_wtrans<<<dim3(8, 8, 24), dim3(32, 8), 0, stream>>>(w_h3,  Wth + OFF_H3,  Wtl + OFF_H3,  256);

  auto gN = [](int N) { return dim3((unsigned)((N + 63) / 64)); };

  auto build_csr = [&](const int* edges, int E, int N) {
    hipMemsetAsync(deg, 0, (size_t)N * sizeof(int), stream);
    k_count<<<(E + 255) / 256, 256, 0, stream>>>(edges, deg, E);
    k_scan<<<1, 1024, 0, stream>>>(deg, rowptr, cursor, N);
    k_fill<<<(E + 255) / 256, 256, 0, stream>>>(edges, cursor, adj, E);
  };

  // 12 fused hidden layers: (A,Hb) <-> (B,D); result pair ends in (A,Hb); x -> B
  auto gconv_hidden = [&](size_t offH, const float* bh, int N) {
    float* R0 = A; float* R1 = Hb; float* S0 = B; float* S1 = D;
    for (int l = 0; l < 12; ++l) {
      const unsigned short* w0h = Wth + offH + (size_t)(2 * l + 0) * 65536;
      const unsigned short* w0l = Wtl + offH + (size_t)(2 * l + 0) * 65536;
      const unsigned short* w1h = Wth + offH + (size_t)(2 * l + 1) * 65536;
      const unsigned short* w1l = Wtl + offH + (size_t)(2 * l + 1) * 65536;
      const float* b0 = bh + (size_t)l * 2 * HID;
      const float* b1 = b0 + HID;
      k_mfma_full<false, true><<<gN(N), 256, 0, stream>>>(
          R0, R1, rowptr, adj, 256, 256, w0h, w0l, w1h, w1l, 256, b0, b1, S0, S1, N);
      std::swap(R0, S0);
      std::swap(R1, S1);
    }
    k_gather_out<<<((size_t)N * 64 + 255) / 256, 256, 0, stream>>>(rowptr, adj, R0, R1, B, N);
  };

  auto gconv_out = [&](const float* X, const float* wo, const float* bo,
                       float* Cdst, const int* edges, int E, int N) {
    k_rowdot3<<<((size_t)N * 64 + 255) / 256, 256, 0, stream>>>(X, wo, bo, Cdst, N);
    k_rowdot3<<<((size_t)N * 64 + 255) / 256, 256, 0, stream>>>(X, wo + HID * 3, bo + 3, C2, N);
    k_scatter3<<<(E + 255) / 256, 256, 0, stream>>>(edges, C2, Cdst, E);
  };

  // ---------- Stage 1 ----------
  build_csr(edges1, E1, N1);
  k_transpose<<<56 * 56, 128, 0, stream>>>(conv64, T, 56 * 56);
  k_vert_align<<<N1, 128, 0, stream>>>(T, verts0, VA, N1, 56, 56);
  k_mfma_full<false, false><<<gN(N1), 256, 0, stream>>>(
      VA, nullptr, nullptr, nullptr, 128, 128,
      Wth + OFF_IN1, Wtl + OFF_IN1, Wth + OFF_IN1 + 32768, Wtl + OFF_IN1 + 32768, 128,
      b_in1, b_in1 + HID, A, Hb, N1);
  gconv_hidden(OFF_H1, b_h1, N1);                     // x -> B
  gconv_out(B, w_out1, b_out1, C0, edges1, E1, N1);   // c1 -> C0
  k_subdiv3<<<(N2 + 255) / 256, 256, 0, stream>>>(C0, edges1, Vv, N1, E1);                   // v2
  k_subdiv_feat<<<((size_t)N2 * 64 + 255) / 256, 256, 0, stream>>>(B, edges1, B, N1, E1);    // hs in B

  // ---------- Stage 2 ----------
  build_csr(edges2, E2, N2);
  k_transpose<<<28 * 28, 128, 0, stream>>>(conv128, T, 28 * 28);
  k_vert_align<<<N2, 128, 0, stream>>>(T, Vv, VA, N2, 28, 28);
  {
    const size_t m0 = OFF_IN2, m1 = OFF_IN2 + (size_t)256 * 384;
    k_mfma_full<false, false><<<gN(N2), 256, 0, stream>>>(
        VA, nullptr, nullptr, nullptr, 128, 128,
        Wth + m0, Wtl + m0, Wth + m1, Wtl + m1, 384, b_in2, b_in2 + HID, A, Hb, N2);
    k_mfma_full<true, false><<<gN(N2), 256, 0, stream>>>(
        B, nullptr, nullptr, nullptr, 256, 256,
        Wth + m0 + 128, Wtl + m0 + 128, Wth + m1 + 128, Wtl + m1 + 128, 384,
        nullptr, nullptr, A, Hb, N2);
  }
  gconv_hidden(OFF_H2, b_h2, N2);                     // x -> B
  gconv_out(B, w_out2, b_out2, C0, edges2, E2, N2);   // c2 -> C0
  k_subdiv3<<<(N3 + 255) / 256, 256, 0, stream>>>(C0, edges2, Vv, N2, E2);                   // v3
  k_subdiv_feat<<<((size_t)N3 * 64 + 255) / 256, 256, 0, stream>>>(B, edges2, B, N2, E2);    // hs in B

  // ---------- Stage 3 ----------
  build_csr(edges3, E3, N3);
  k_transpose<<<14 * 14, 128, 0, stream>>>(conv256, T, 14 * 14);
  k_vert_align<<<N3, 128, 0, stream>>>(T, Vv, VA, N3, 14, 14);
  {
    const size_t m0 = OFF_IN3, m1 = OFF_IN3 + (size_t)256 * 384;
    k_mfma_full<false, false><<<gN(N3), 256, 0, stream>>>(
        VA, nullptr, nullptr, nullptr, 128, 128,
        Wth + m0, Wtl + m0, Wth + m1, Wtl + m1, 384, b_in3, b_in3 + HID, A, Hb, N3);
    k_mfma_full<true, false><<<gN(N3), 256, 0, stream>>>(
        B, nullptr, nullptr, nullptr, 256, 256,
        Wth + m0 + 128, Wtl + m0 + 128, Wth + m1 + 128, Wtl + m1 + 128, 384,
        nullptr, nullptr, A, Hb, N3);
  }
  gconv_hidden(OFF_H3, b_h3, N3);                     // x -> B
  float* OUT = (float*)d_out;
  k_rowdot3<<<((size_t)N3 * 64 + 255) / 256, 256, 0, stream>>>(B, w_out3, b_out3, OUT, N3);
  k_rowdot3<<<((size_t)N3 * 64 + 255) / 256, 256, 0, stream>>>(B, w_out3 + HID * 3, b_out3 + 3, C2, N3);
  k_scatter3<<<(E3 + 255) / 256, 256, 0, stream>>>(edges3, C2, OUT, E3);
}

// Round 6
// 5585.988 us; speedup vs baseline: 1.5495x; 1.5495x over previous
//
#include <hip/hip_runtime.h>
#include <utility>

#define HID 256

typedef __attribute__((ext_vector_type(8))) short bf16x8;
typedef __attribute__((ext_vector_type(4))) float f32x4;
typedef __attribute__((ext_vector_type(4))) unsigned short us4;

// Topology constants for GRID_N=80
constexpr size_t MAXN3 = 100489;
constexpr size_t MAXE3 = 300200;

// Transposed-weight scratch offsets (elements). Layout per matrix: [256 n][K k].
constexpr size_t OFF_IN1 = 0;                       // 2 mats K=128
constexpr size_t OFF_IN2 = OFF_IN1 + 2 * 256 * 128; // 2 mats K=384
constexpr size_t OFF_IN3 = OFF_IN2 + 2 * 256 * 384;
constexpr size_t OFF_H1  = OFF_IN3 + 2 * 256 * 384; // 24 mats K=256
constexpr size_t OFF_H2  = OFF_H1 + 24 * 256 * 256;
constexpr size_t OFF_H3  = OFF_H2 + 24 * 256 * 256;
constexpr size_t WT_TOTAL = OFF_H3 + 24 * 256 * 256;

// Static device scratch (BSS — graph-capture safe).
__device__ float g_A [MAXN3 * 256];
__device__ float g_B [MAXN3 * 256];
__device__ float g_G [MAXN3 * 256];   // gathered A·X
__device__ float g_D [MAXN3 * 256];   // hs (subdivided features)
__device__ float g_VA[MAXN3 * 128];
__device__ float g_C0[MAXN3 * 3];
__device__ float g_C2[MAXN3 * 3];
__device__ float g_Vv[MAXN3 * 3];
__device__ float g_T [56 * 56 * 128];
__device__ unsigned short g_Wth[WT_TOTAL];
__device__ unsigned short g_Wtl[WT_TOTAL];
// CSR scratch
__device__ int g_deg   [MAXN3];
__device__ int g_rowptr[MAXN3 + 1];
__device__ int g_cursor[MAXN3];
__device__ int g_adj   [2 * MAXE3];

// ---------------- weight transpose + bf16 hi/lo split ----------------
__global__ __launch_bounds__(256) void k_wtrans(const float* __restrict__ W,
                                                unsigned short* __restrict__ Oh,
                                                unsigned short* __restrict__ Ol,
                                                int K) {
  __shared__ float t[32][33];
  int mat = blockIdx.z;
  const float* Wm = W + (size_t)mat * K * 256;
  unsigned short* OhM = Oh + (size_t)mat * K * 256;
  unsigned short* OlM = Ol + (size_t)mat * K * 256;
  int x = threadIdx.x;
  int y = threadIdx.y;
  int k0 = blockIdx.x * 32, n0 = blockIdx.y * 32;
#pragma unroll
  for (int i = 0; i < 4; ++i) {
    int kk = y + i * 8;
    t[kk][x] = Wm[(size_t)(k0 + kk) * 256 + n0 + x];
  }
  __syncthreads();
#pragma unroll
  for (int i = 0; i < 4; ++i) {
    int nn = y + i * 8;
    float v = t[x][nn];
    unsigned u = __float_as_uint(v);
    unsigned short hi = (unsigned short)(u >> 16);
    float hv = __uint_as_float((unsigned)hi << 16);
    unsigned short lo = (unsigned short)(__float_as_uint(v - hv) >> 16);
    OhM[(size_t)(n0 + nn) * K + k0 + x] = hi;
    OlM[(size_t)(n0 + nn) * K + k0 + x] = lo;
  }
}

// ---------------- CSR build ----------------

__global__ __launch_bounds__(256) void k_count(const int* __restrict__ edges,
                                               int* __restrict__ deg, int E) {
  int e = blockIdx.x * blockDim.x + threadIdx.x;
  if (e >= E) return;
  atomicAdd(&deg[edges[2 * e + 0]], 1);
  atomicAdd(&deg[edges[2 * e + 1]], 1);
}

__global__ __launch_bounds__(1024) void k_scan(const int* __restrict__ deg,
                                               int* __restrict__ rowptr,
                                               int* __restrict__ cursor, int N) {
  __shared__ int sums[1024];
  int t = threadIdx.x;
  int chunk = (N + 1023) / 1024;
  int lo = t * chunk;
  int hi = min(lo + chunk, N);
  int s = 0;
  for (int i = lo; i < hi; ++i) s += deg[i];
  sums[t] = s;
  __syncthreads();
  for (int off = 1; off < 1024; off <<= 1) {
    int v = (t >= off) ? sums[t - off] : 0;
    __syncthreads();
    sums[t] += v;
    __syncthreads();
  }
  int base = (t == 0) ? 0 : sums[t - 1];
  for (int i = lo; i < hi; ++i) {
    rowptr[i] = base;
    cursor[i] = base;
    base += deg[i];
  }
  if (t == 1023) rowptr[N] = sums[1023];
}

__global__ __launch_bounds__(256) void k_fill(const int* __restrict__ edges,
                                              int* __restrict__ cursor,
                                              int* __restrict__ adj, int E) {
  int e = blockIdx.x * blockDim.x + threadIdx.x;
  if (e >= E) return;
  int a = edges[2 * e + 0];
  int b = edges[2 * e + 1];
  adj[atomicAdd(&cursor[a], 1)] = b;
  adj[atomicAdd(&cursor[b], 1)] = a;
}

// ---------------- misc kernels ----------------

__global__ __launch_bounds__(128) void k_transpose(const float* __restrict__ in,
                                                   float* __restrict__ out, int HW) {
  int p = blockIdx.x;
  int c = threadIdx.x;
  if (p < HW) out[(size_t)p * 128 + c] = in[(size_t)c * HW + p];
}

__global__ __launch_bounds__(128) void k_vert_align(const float* __restrict__ fT,
                                                    const float* __restrict__ verts,
                                                    float* __restrict__ out,
                                                    int N, int H, int W) {
  int v = blockIdx.x;
  if (v >= N) return;
  int c = threadIdx.x;
  float vx = verts[(size_t)v * 3 + 0];
  float vy = verts[(size_t)v * 3 + 1];
  float fx = (vx + 1.f) * 0.5f * (float)(W - 1);
  float fy = (vy + 1.f) * 0.5f * (float)(H - 1);
  float x0f = floorf(fx), y0f = floorf(fy);
  float wx = fx - x0f, wy = fy - y0f;
  int x0 = (int)x0f, y0 = (int)y0f;
  float acc = 0.f;
#pragma unroll
  for (int dy = 0; dy < 2; ++dy) {
#pragma unroll
    for (int dx = 0; dx < 2; ++dx) {
      int yi = y0 + dy, xi = x0 + dx;
      bool valid = (yi >= 0) && (yi < H) && (xi >= 0) && (xi < W);
      int yc = min(max(yi, 0), H - 1);
      int xc = min(max(xi, 0), W - 1);
      float val = fT[((size_t)yc * W + xc) * 128 + c];
      float wgt = (dy ? wy : 1.f - wy) * (dx ? wx : 1.f - wx);
      acc += valid ? val * wgt : 0.f;
    }
  }
  out[(size_t)v * 128 + c] = acc;
}

// G[v] = sum_{u in adj(v)} X[u]   (CH channels)
template <int CH>
__global__ __launch_bounds__(256) void k_gather(const int* __restrict__ rowptr,
                                                const int* __restrict__ adj,
                                                const float* __restrict__ X,
                                                float* __restrict__ G, int N) {
  int idx = blockIdx.x * blockDim.x + threadIdx.x;
  int v = idx / (CH / 4);
  if (v >= N) return;
  int c = (idx % (CH / 4)) * 4;
  float4 acc = make_float4(0.f, 0.f, 0.f, 0.f);
  int lo = rowptr[v], hi = rowptr[v + 1];
  for (int i = lo; i < hi; ++i) {
    float4 h = *(const float4*)(X + (size_t)adj[i] * CH + c);
    acc.x += h.x; acc.y += h.y; acc.z += h.z; acc.w += h.w;
  }
  *(float4*)(G + (size_t)v * CH + c) = acc;
}

// ---------------- concat-panel MFMA split-bf16 layer ----------------
// Y[64r x 256c tile] = concat_panels(X...) @ [W0;W1](transposed, hi/lo split)
//                      + b0 + deg*b1
// Panels: up to 4 f32 sources; boundaries multiples of 64.
struct Panels {
  const float* p[4];
  int ks[4];   // start-k of panels 1..3 in ks[1..3]; unused = INT_MAX; ks[0]=0
  int ld[4];
};

#define SWZ(row, slot) (((row) * 64) + (((slot) ^ ((row) & 7)) * 8))

__global__ __launch_bounds__(256) void k_layer(
    Panels pd, int Kmm,
    const unsigned short* __restrict__ w0h, const unsigned short* __restrict__ w0l,
    const unsigned short* __restrict__ w1h, const unsigned short* __restrict__ w1l,
    int Kw,
    const float* __restrict__ b0, const float* __restrict__ b1,
    const int* __restrict__ deg,
    float* __restrict__ Y, int N) {
  __shared__ unsigned short lds[4][64 * 64]; // xh, xl, wh, wl
  int tid = threadIdx.x;
  int lane = tid & 63;
  int wid = tid >> 6;
  int wm = wid & 1, wn = wid >> 1;

  // XCD-aware swizzle: 4 col-blocks of one row-tile -> same XCD (i%8 heuristic)
  int nrt = (N + 63) >> 6;
  int total = nrt * 4;
  int flat = blockIdx.x;
  int rowtile, colblk;
  if ((flat & ~31) + 32 <= total) {
    int sub = flat & 31;
    rowtile = (flat >> 5) * 8 + (sub & 7);
    colblk = sub >> 3;
  } else {
    rowtile = flat >> 2;
    colblk = flat & 3;
  }
  int row0 = rowtile * 64;
  int col0 = colblk * 64;

  f32x4 acc[2][2];
#pragma unroll
  for (int m = 0; m < 2; ++m)
#pragma unroll
    for (int n = 0; n < 2; ++n) acc[m][n] = (f32x4){0.f, 0.f, 0.f, 0.f};

  for (int kt = 0; kt < Kmm; kt += 64) {
    // panel select (wave-uniform)
    int pi = (kt >= pd.ks[1]) + (kt >= pd.ks[2]) + (kt >= pd.ks[3]);
    const float* base = pd.p[pi];
    int ld = pd.ld[pi];
    int koff = kt - pd.ks[pi];
    // stage X tile (f32 -> bf16 hi/lo, swizzled)
#pragma unroll
    for (int it = 0; it < 4; ++it) {
      int linear = tid + it * 256;
      int row = linear >> 4;
      int c4 = (linear & 15) * 4;
      int v = row0 + row;
      float4 xv = make_float4(0.f, 0.f, 0.f, 0.f);
      if (v < N) xv = *(const float4*)(base + (size_t)v * ld + koff + c4);
      us4 hv, lv;
#pragma unroll
      for (int j = 0; j < 4; ++j) {
        float f = (&xv.x)[j];
        unsigned u = __float_as_uint(f);
        unsigned short hi16 = (unsigned short)(u >> 16);
        float hf = __uint_as_float((unsigned)hi16 << 16);
        unsigned short lo16 = (unsigned short)(__float_as_uint(f - hf) >> 16);
        hv[j] = hi16;
        lv[j] = lo16;
      }
      int s = c4 >> 3, half = (c4 >> 2) & 1;
      int off = SWZ(row, s) + half * 4;
      *(us4*)&lds[0][off] = hv;
      *(us4*)&lds[1][off] = lv;
    }
    // weight select (wave-uniform) + stage (bf16, swizzled)
    const unsigned short* wh = (kt < Kw) ? w0h : w1h;
    const unsigned short* wl = (kt < Kw) ? w0l : w1l;
    int wk = (kt < Kw) ? kt : kt - Kw;
#pragma unroll
    for (int it = 0; it < 2; ++it) {
      int linear = tid + it * 256;
      int n = linear >> 3;
      int slot = linear & 7;
      uint4 vh = *(const uint4*)(wh + (size_t)(col0 + n) * Kw + wk + slot * 8);
      uint4 vl = *(const uint4*)(wl + (size_t)(col0 + n) * Kw + wk + slot * 8);
      *(uint4*)&lds[2][SWZ(n, slot)] = vh;
      *(uint4*)&lds[3][SWZ(n, slot)] = vl;
    }
    __syncthreads();
#pragma unroll
    for (int ks = 0; ks < 2; ++ks) {
      int slot = ks * 4 + (lane >> 4);
      bf16x8 ah[2], al[2], bh[2], bl[2];
#pragma unroll
      for (int m = 0; m < 2; ++m) {
        int row = wm * 32 + m * 16 + (lane & 15);
        ah[m] = *(const bf16x8*)&lds[0][SWZ(row, slot)];
        al[m] = *(const bf16x8*)&lds[1][SWZ(row, slot)];
      }
#pragma unroll
      for (int n = 0; n < 2; ++n) {
        int nr = wn * 32 + n * 16 + (lane & 15);
        bh[n] = *(const bf16x8*)&lds[2][SWZ(nr, slot)];
        bl[n] = *(const bf16x8*)&lds[3][SWZ(nr, slot)];
      }
#pragma unroll
      for (int m = 0; m < 2; ++m)
#pragma unroll
        for (int n = 0; n < 2; ++n) {
          f32x4 c = acc[m][n];
          c = __builtin_amdgcn_mfma_f32_16x16x32_bf16(al[m], bh[n], c, 0, 0, 0);
          c = __builtin_amdgcn_mfma_f32_16x16x32_bf16(ah[m], bl[n], c, 0, 0, 0);
          c = __builtin_amdgcn_mfma_f32_16x16x32_bf16(ah[m], bh[n], c, 0, 0, 0);
          acc[m][n] = c;
        }
    }
    __syncthreads();
  }

  // epilogue: bias = b0[col] + deg[row]*b1[col]
#pragma unroll
  for (int m = 0; m < 2; ++m)
#pragma unroll
    for (int n = 0; n < 2; ++n) {
      int col = col0 + wn * 32 + n * 16 + (lane & 15);
      int rbase = row0 + wm * 32 + m * 16 + (lane >> 4) * 4;
      float bb0 = b0[col], bb1 = b1[col];
      f32x4 v = acc[m][n];
#pragma unroll
      for (int r = 0; r < 4; ++r) {
        int row = rbase + r;
        if (row < N)
          Y[(size_t)row * HID + col] = v[r] + bb0 + (float)deg[row] * bb1;
      }
    }
}

__global__ __launch_bounds__(256) void k_rowdot3(const float* __restrict__ X,
                                                 const float* __restrict__ W,
                                                 const float* __restrict__ b,
                                                 float* __restrict__ Y, int N) {
  int gid = blockIdx.x * blockDim.x + threadIdx.x;
  int row = gid >> 6;
  int lane = threadIdx.x & 63;
  if (row >= N) return;
  float4 xv = ((const float4*)(X + (size_t)row * HID))[lane];
  float s0 = 0.f, s1 = 0.f, s2 = 0.f;
#pragma unroll
  for (int k = 0; k < 4; ++k) {
    float x = (&xv.x)[k];
    int kk = lane * 4 + k;
    s0 += x * W[kk * 3 + 0];
    s1 += x * W[kk * 3 + 1];
    s2 += x * W[kk * 3 + 2];
  }
#pragma unroll
  for (int off = 32; off > 0; off >>= 1) {
    s0 += __shfl_down(s0, off);
    s1 += __shfl_down(s1, off);
    s2 += __shfl_down(s2, off);
  }
  if (lane == 0) {
    Y[(size_t)row * 3 + 0] = s0 + b[0];
    Y[(size_t)row * 3 + 1] = s1 + b[1];
    Y[(size_t)row * 3 + 2] = s2 + b[2];
  }
}

__global__ __launch_bounds__(256) void k_scatter3(const int* __restrict__ edges,
                                                  const float* __restrict__ H,
                                                  float* __restrict__ OUT, int E) {
  int e = blockIdx.x * blockDim.x + threadIdx.x;
  if (e >= E) return;
  int a = edges[(size_t)e * 2 + 0];
  int b = edges[(size_t)e * 2 + 1];
#pragma unroll
  for (int k = 0; k < 3; ++k) {
    atomicAdd(&OUT[(size_t)a * 3 + k], H[(size_t)b * 3 + k]);
    atomicAdd(&OUT[(size_t)b * 3 + k], H[(size_t)a * 3 + k]);
  }
}

__global__ __launch_bounds__(256) void k_subdiv3(const float* __restrict__ c,
                                                 const int* __restrict__ edges,
                                                 float* __restrict__ v, int N, int E) {
  int i = blockIdx.x * blockDim.x + threadIdx.x;
  if (i >= N + E) return;
  if (i < N) {
#pragma unroll
    for (int k = 0; k < 3; ++k) v[(size_t)i * 3 + k] = c[(size_t)i * 3 + k];
  } else {
    int e = i - N;
    int a = edges[(size_t)e * 2 + 0];
    int b = edges[(size_t)e * 2 + 1];
#pragma unroll
    for (int k = 0; k < 3; ++k)
      v[(size_t)i * 3 + k] = 0.5f * (c[(size_t)a * 3 + k] + c[(size_t)b * 3 + k]);
  }
}

__global__ __launch_bounds__(256) void k_subdiv_feat(const float* __restrict__ x,
                                                     const int* __restrict__ edges,
                                                     float* __restrict__ out, int N, int E) {
  int idx = blockIdx.x * blockDim.x + threadIdx.x;
  int v = idx >> 6;
  if (v >= N + E) return;
  int c = (threadIdx.x & 63) * 4;
  float4 r;
  if (v < N) {
    r = *(const float4*)(x + (size_t)v * HID + c);
  } else {
    int e = v - N;
    int a = edges[(size_t)e * 2 + 0];
    int b = edges[(size_t)e * 2 + 1];
    float4 xa = *(const float4*)(x + (size_t)a * HID + c);
    float4 xb = *(const float4*)(x + (size_t)b * HID + c);
    r = make_float4(0.5f * (xa.x + xb.x), 0.5f * (xa.y + xb.y),
                    0.5f * (xa.z + xb.z), 0.5f * (xa.w + xb.w));
  }
  *(float4*)(out + (size_t)v * HID + c) = r;
}

// ---------------- launcher ----------------

extern "C" void kernel_launch(void* const* d_in, const int* in_sizes, int n_in,
                              void* d_out, int out_size, void* d_ws, size_t ws_size,
                              hipStream_t stream) {
  const float* conv64  = (const float*)d_in[0];
  const float* conv128 = (const float*)d_in[1];
  const float* conv256 = (const float*)d_in[2];
  const float* verts0  = (const float*)d_in[3];
  const int*   edges1  = (const int*)d_in[4];
  const int*   edges2  = (const int*)d_in[5];
  const int*   edges3  = (const int*)d_in[6];
  const float* w_in1 = (const float*)d_in[7],  *b_in1 = (const float*)d_in[8];
  const float* w_h1  = (const float*)d_in[9],  *b_h1  = (const float*)d_in[10];
  const float* w_out1= (const float*)d_in[11], *b_out1= (const float*)d_in[12];
  const float* w_in2 = (const float*)d_in[13], *b_in2 = (const float*)d_in[14];
  const float* w_h2  = (const float*)d_in[15], *b_h2  = (const float*)d_in[16];
  const float* w_out2= (const float*)d_in[17], *b_out2= (const float*)d_in[18];
  const float* w_in3 = (const float*)d_in[19], *b_in3 = (const float*)d_in[20];
  const float* w_h3  = (const float*)d_in[21], *b_h3  = (const float*)d_in[22];
  const float* w_out3= (const float*)d_in[23], *b_out3= (const float*)d_in[24];

  const int N1 = in_sizes[3] / 3;
  const int E1 = in_sizes[4] / 2;
  const int E2 = in_sizes[5] / 2;
  const int E3 = in_sizes[6] / 2;
  const int N2 = N1 + E1;
  const int N3 = N2 + E2;
  if ((size_t)N3 > MAXN3 || (size_t)E3 > MAXE3) return;

  float *A, *B, *G, *D, *VA, *C0, *C2, *Vv, *T;
  unsigned short *Wth, *Wtl;
  int *deg, *rowptr, *cursor, *adj;
  hipGetSymbolAddress((void**)&A,  HIP_SYMBOL(g_A));
  hipGetSymbolAddress((void**)&B,  HIP_SYMBOL(g_B));
  hipGetSymbolAddress((void**)&G,  HIP_SYMBOL(g_G));
  hipGetSymbolAddress((void**)&D,  HIP_SYMBOL(g_D));
  hipGetSymbolAddress((void**)&VA, HIP_SYMBOL(g_VA));
  hipGetSymbolAddress((void**)&C0, HIP_SYMBOL(g_C0));
  hipGetSymbolAddress((void**)&C2, HIP_SYMBOL(g_C2));
  hipGetSymbolAddress((void**)&Vv, HIP_SYMBOL(g_Vv));
  hipGetSymbolAddress((void**)&T,  HIP_SYMBOL(g_T));
  hipGetSymbolAddress((void**)&Wth, HIP_SYMBOL(g_Wth));
  hipGetSymbolAddress((void**)&Wtl, HIP_SYMBOL(g_Wtl));
  hipGetSymbolAddress((void**)&deg,    HIP_SYMBOL(g_deg));
  hipGetSymbolAddress((void**)&rowptr, HIP_SYMBOL(g_rowptr));
  hipGetSymbolAddress((void**)&cursor, HIP_SYMBOL(g_cursor));
  hipGetSymbolAddress((void**)&adj,    HIP_SYMBOL(g_adj));

  // ---- weight transpose + split (once per launch, deterministic) ----
  k_wtrans<<<dim3(4, 8, 2),  dim3(32, 8), 0, stream>>>(w_in1, Wth + OFF_IN1, Wtl + OFF_IN1, 128);
  k_wtrans<<<dim3(12, 8, 2), dim3(32, 8), 0, stream>>>(w_in2, Wth + OFF_IN2, Wtl + OFF_IN2, 384);
  k_wtrans<<<dim3(12, 8, 2), dim3(32, 8), 0, stream>>>(w_in3, Wth + OFF_IN3, Wtl + OFF_IN3, 384);
  k_wtrans<<<dim3(8, 8, 24), dim3(32, 8), 0, stream>>>(w_h1,  Wth + OFF_H1,  Wtl + OFF_H1,  256);
  k_wtrans<<<dim3(8, 8, 24), dim3(32, 8), 0, stream>>>(w_h2,  Wth + OFF_H2,  Wtl + OFF_H2,  256);
  k_wtrans<<<dim3(8, 8, 24), dim3(32, 8), 0, stream>>>(w_h3,  Wth + OFF_H3,  Wtl + OFF_H3,  256);

  const int BIG = 0x7fffffff;

  auto layerGrid = [](int N) { return dim3((unsigned)(((N + 63) / 64) * 4)); };

  auto build_csr = [&](const int* edges, int E, int N) {
    hipMemsetAsync(deg, 0, (size_t)N * sizeof(int), stream);
    k_count<<<(E + 255) / 256, 256, 0, stream>>>(edges, deg, E);
    k_scan<<<1, 1024, 0, stream>>>(deg, rowptr, cursor, N);
    k_fill<<<(E + 255) / 256, 256, 0, stream>>>(edges, cursor, adj, E);
  };

  // 12 hidden layers: x' = [X | A·X] @ [W0;W1] + b0 + deg*b1 ; X ping-pongs A<->B
  auto gconv_hidden = [&](size_t offH, const float* bh, int N) {
    float* X = A; float* Y = B;
    for (int l = 0; l < 12; ++l) {
      const unsigned short* w0h = Wth + offH + (size_t)(2 * l + 0) * 65536;
      const unsigned short* w0l = Wtl + offH + (size_t)(2 * l + 0) * 65536;
      const unsigned short* w1h = Wth + offH + (size_t)(2 * l + 1) * 65536;
      const unsigned short* w1l = Wtl + offH + (size_t)(2 * l + 1) * 65536;
      const float* b0 = bh + (size_t)l * 2 * HID;
      const float* b1 = b0 + HID;
      k_gather<256><<<((size_t)N * 64 + 255) / 256, 256, 0, stream>>>(rowptr, adj, X, G, N);
      Panels pd = {{X, G, nullptr, nullptr}, {0, 256, BIG, BIG}, {256, 256, 0, 0}};
      k_layer<<<layerGrid(N), 256, 0, stream>>>(pd, 512, w0h, w0l, w1h, w1l, 256,
                                                b0, b1, deg, Y, N);
      std::swap(X, Y);
    }
    // x ends in A (12 swaps)
  };

  auto gconv_out = [&](const float* X, const float* wo, const float* bo,
                       float* Cdst, const int* edges, int E, int N) {
    k_rowdot3<<<((size_t)N * 64 + 255) / 256, 256, 0, stream>>>(X, wo, bo, Cdst, N);
    k_rowdot3<<<((size_t)N * 64 + 255) / 256, 256, 0, stream>>>(X, wo + HID * 3, bo + 3, C2, N);
    k_scatter3<<<(E + 255) / 256, 256, 0, stream>>>(edges, C2, Cdst, E);
  };

  // ---------- Stage 1 ----------
  build_csr(edges1, E1, N1);
  k_transpose<<<56 * 56, 128, 0, stream>>>(conv64, T, 56 * 56);
  k_vert_align<<<N1, 128, 0, stream>>>(T, verts0, VA, N1, 56, 56);
  // in-layer: x0 = [VA | A·VA] @ [Win0;Win1] + b0 + deg*b1
  k_gather<128><<<((size_t)N1 * 32 + 255) / 256, 256, 0, stream>>>(rowptr, adj, VA, G, N1);
  {
    Panels pd = {{VA, G, nullptr, nullptr}, {0, 128, BIG, BIG}, {128, 128, 0, 0}};
    k_layer<<<layerGrid(N1), 256, 0, stream>>>(pd, 256,
        Wth + OFF_IN1, Wtl + OFF_IN1, Wth + OFF_IN1 + 32768, Wtl + OFF_IN1 + 32768, 128,
        b_in1, b_in1 + HID, deg, A, N1);
  }
  gconv_hidden(OFF_H1, b_h1, N1);                     // x -> A
  gconv_out(A, w_out1, b_out1, C0, edges1, E1, N1);   // c1 -> C0
  k_subdiv3<<<(N2 + 255) / 256, 256, 0, stream>>>(C0, edges1, Vv, N1, E1);                 // v2
  k_subdiv_feat<<<((size_t)N2 * 64 + 255) / 256, 256, 0, stream>>>(A, edges1, D, N1, E1);  // hs -> D

  // ---------- Stage 2 ----------
  build_csr(edges2, E2, N2);
  k_transpose<<<28 * 28, 128, 0, stream>>>(conv128, T, 28 * 28);
  k_vert_align<<<N2, 128, 0, stream>>>(T, Vv, VA, N2, 28, 28);
  k_gather<128><<<((size_t)N2 * 32 + 255) / 256, 256, 0, stream>>>(rowptr, adj, VA, G, N2);
  k_gather<256><<<((size_t)N2 * 64 + 255) / 256, 256, 0, stream>>>(rowptr, adj, D, B, N2);
  {
    const size_t m0 = OFF_IN2, m1 = OFF_IN2 + (size_t)256 * 384;
    Panels pd = {{VA, D, G, B}, {0, 128, 384, 512}, {128, 256, 128, 256}};
    k_layer<<<layerGrid(N2), 256, 0, stream>>>(pd, 768,
        Wth + m0, Wtl + m0, Wth + m1, Wtl + m1, 384,
        b_in2, b_in2 + HID, deg, A, N2);
  }
  gconv_hidden(OFF_H2, b_h2, N2);                     // x -> A
  gconv_out(A, w_out2, b_out2, C0, edges2, E2, N2);   // c2 -> C0
  k_subdiv3<<<(N3 + 255) / 256, 256, 0, stream>>>(C0, edges2, Vv, N2, E2);                 // v3
  k_subdiv_feat<<<((size_t)N3 * 64 + 255) / 256, 256, 0, stream>>>(A, edges2, D, N2, E2);  // hs -> D

  // ---------- Stage 3 ----------
  build_csr(edges3, E3, N3);
  k_transpose<<<14 * 14, 128, 0, stream>>>(conv256, T, 14 * 14);
  k_vert_align<<<N3, 128, 0, stream>>>(T, Vv, VA, N3, 14, 14);
  k_gather<128><<<((size_t)N3 * 32 + 255) / 256, 256, 0, stream>>>(rowptr, adj, VA, G, N3);
  k_gather<256><<<((size_t)N3 * 64 + 255) / 256, 256, 0, stream>>>(rowptr, adj, D, B, N3);
  {
    const size_t m0 = OFF_IN3, m1 = OFF_IN3 + (size_t)256 * 384;
    Panels pd = {{VA, D, G, B}, {0, 128, 384, 512}, {128, 256, 128, 256}};
    k_layer<<<layerGrid(N3), 256, 0, stream>>>(pd, 768,
        Wth + m0, Wtl + m0, Wth + m1, Wtl + m1, 384,
        b_in3, b_in3 + HID, deg, A, N3);
  }
  gconv_hidden(OFF_H3, b_h3, N3);                     // x -> A
  float* OUT = (float*)d_out;
  k_rowdot3<<<((size_t)N3 * 64 + 255) / 256, 256, 0, stream>>>(A, w_out3, b_out3, OUT, N3);
  k_rowdot3<<<((size_t)N3 * 64 + 255) / 256, 256, 0, stream>>>(A, w_out3 + HID * 3, b_out3 + 3, C2, N3);
  k_scatter3<<<(E3 + 255) / 256, 256, 0, stream>>>(edges3, C2, OUT, E3);
}

// Round 7
// 4869.522 us; speedup vs baseline: 1.7775x; 1.1471x over previous
//
#include <hip/hip_runtime.h>
#include <utility>

#define HID 256

typedef __attribute__((ext_vector_type(8))) short bf16x8;
typedef __attribute__((ext_vector_type(4))) float f32x4;
typedef __attribute__((ext_vector_type(4))) unsigned short us4;
typedef __attribute__((ext_vector_type(4))) unsigned uint4v;

// Topology constants for GRID_N=80
constexpr size_t MAXN3 = 100489;
constexpr size_t MAXE3 = 300200;

// Tiled-weight offsets (elements). Per matrix: [4 cb][K/64 ktb][4096 bf16],
// tile content pre-swizzled so a LINEAR global_load_lds produces the SWZ image.
constexpr size_t OFF_IN1 = 0;                       // 2 mats K=128
constexpr size_t OFF_IN2 = OFF_IN1 + 2 * 256 * 128; // 2 mats K=384
constexpr size_t OFF_IN3 = OFF_IN2 + 2 * 256 * 384;
constexpr size_t OFF_H1  = OFF_IN3 + 2 * 256 * 384; // 24 mats K=256
constexpr size_t OFF_H2  = OFF_H1 + 24 * 256 * 256;
constexpr size_t OFF_H3  = OFF_H2 + 24 * 256 * 256;
constexpr size_t WT_TOTAL = OFF_H3 + 24 * 256 * 256;

// Static device scratch (BSS — graph-capture safe). Feature buffers hold
// PACKED hi/lo bf16 pairs in one u32 (hi in top half): x == rec(u) exactly.
__device__ __attribute__((aligned(16))) unsigned g_A [MAXN3 * 256];
__device__ __attribute__((aligned(16))) unsigned g_B [MAXN3 * 256];
__device__ __attribute__((aligned(16))) unsigned g_G [MAXN3 * 256];
__device__ __attribute__((aligned(16))) unsigned g_D [MAXN3 * 256];
__device__ __attribute__((aligned(16))) unsigned g_VA[MAXN3 * 128];
__device__ float g_C0[MAXN3 * 3];
__device__ float g_C2[MAXN3 * 3];
__device__ float g_Vv[MAXN3 * 3];
__device__ float g_T [56 * 56 * 128];
__device__ __attribute__((aligned(16))) unsigned short g_Wth[WT_TOTAL];
__device__ __attribute__((aligned(16))) unsigned short g_Wtl[WT_TOTAL];
// CSR scratch
__device__ int g_deg   [MAXN3];
__device__ int g_rowptr[MAXN3 + 1];
__device__ int g_cursor[MAXN3];
__device__ int g_adj   [2 * MAXE3];

__device__ inline float rec(unsigned u) {
  return __uint_as_float(u & 0xffff0000u) + __uint_as_float(u << 16);
}
__device__ inline unsigned pck(float f) {
  unsigned u = __float_as_uint(f);
  unsigned hi = u & 0xffff0000u;
  unsigned lo = __float_as_uint(f - __uint_as_float(hi)) >> 16;
  return hi | (lo & 0xffffu);
}

#define GLOAD16(g, l)                                                       \
  __builtin_amdgcn_global_load_lds(                                        \
      (const __attribute__((address_space(1))) unsigned*)(g),              \
      (__attribute__((address_space(3))) unsigned*)(l), 16, 0, 0)

// ---------------- weight transpose + split + tile-swizzle ----------------
// Out tile chunk c (n=c>>3, sp=c&7) holds W^T[cb*64+n][ktb*64+(sp^(n&7))*8 .. +7]
__global__ __launch_bounds__(256) void k_wtrans(const float* __restrict__ W,
                                                unsigned short* __restrict__ Oh,
                                                unsigned short* __restrict__ Ol,
                                                int K) {
  __shared__ float Ls[64][65];
  int ktb = blockIdx.x, cb = blockIdx.y, mat = blockIdx.z;
  int nktb = gridDim.x;
  const float* Wm = W + (size_t)mat * K * 256;
  int t = threadIdx.x;
#pragma unroll
  for (int i = 0; i < 16; ++i) {
    int idx = i * 256 + t;
    int kk = idx >> 6, cc = idx & 63;
    Ls[kk][cc] = Wm[(size_t)(ktb * 64 + kk) * 256 + cb * 64 + cc];
  }
  __syncthreads();
  size_t tb = ((size_t)(mat * 4 + cb) * nktb + ktb) * 4096;
#pragma unroll
  for (int i = 0; i < 2; ++i) {
    int c = t * 2 + i;
    int n = c >> 3, sp = c & 7;
    int kbase = (sp ^ (n & 7)) * 8;
    unsigned short hb[8], lb[8];
#pragma unroll
    for (int j = 0; j < 8; ++j) {
      float v = Ls[kbase + j][n];
      unsigned u = __float_as_uint(v);
      unsigned short hi = (unsigned short)(u >> 16);
      float hf = __uint_as_float(u & 0xffff0000u);
      hb[j] = hi;
      lb[j] = (unsigned short)(__float_as_uint(v - hf) >> 16);
    }
    *(us4*)(Oh + tb + c * 8)     = (us4){hb[0], hb[1], hb[2], hb[3]};
    *(us4*)(Oh + tb + c * 8 + 4) = (us4){hb[4], hb[5], hb[6], hb[7]};
    *(us4*)(Ol + tb + c * 8)     = (us4){lb[0], lb[1], lb[2], lb[3]};
    *(us4*)(Ol + tb + c * 8 + 4) = (us4){lb[4], lb[5], lb[6], lb[7]};
  }
}

// ---------------- CSR build ----------------

__global__ __launch_bounds__(256) void k_count(const int* __restrict__ edges,
                                               int* __restrict__ deg, int E) {
  int e = blockIdx.x * blockDim.x + threadIdx.x;
  if (e >= E) return;
  atomicAdd(&deg[edges[2 * e + 0]], 1);
  atomicAdd(&deg[edges[2 * e + 1]], 1);
}

__global__ __launch_bounds__(1024) void k_scan(const int* __restrict__ deg,
                                               int* __restrict__ rowptr,
                                               int* __restrict__ cursor, int N) {
  __shared__ int sums[1024];
  int t = threadIdx.x;
  int chunk = (N + 1023) / 1024;
  int lo = t * chunk;
  int hi = min(lo + chunk, N);
  int s = 0;
  for (int i = lo; i < hi; ++i) s += deg[i];
  sums[t] = s;
  __syncthreads();
  for (int off = 1; off < 1024; off <<= 1) {
    int v = (t >= off) ? sums[t - off] : 0;
    __syncthreads();
    sums[t] += v;
    __syncthreads();
  }
  int base = (t == 0) ? 0 : sums[t - 1];
  for (int i = lo; i < hi; ++i) {
    rowptr[i] = base;
    cursor[i] = base;
    base += deg[i];
  }
  if (t == 1023) rowptr[N] = sums[1023];
}

__global__ __launch_bounds__(256) void k_fill(const int* __restrict__ edges,
                                              int* __restrict__ cursor,
                                              int* __restrict__ adj, int E) {
  int e = blockIdx.x * blockDim.x + threadIdx.x;
  if (e >= E) return;
  int a = edges[2 * e + 0];
  int b = edges[2 * e + 1];
  adj[atomicAdd(&cursor[a], 1)] = b;
  adj[atomicAdd(&cursor[b], 1)] = a;
}

// ---------------- misc kernels ----------------

__global__ __launch_bounds__(128) void k_transpose(const float* __restrict__ in,
                                                   float* __restrict__ out, int HW) {
  int p = blockIdx.x;
  int c = threadIdx.x;
  if (p < HW) out[(size_t)p * 128 + c] = in[(size_t)c * HW + p];
}

__global__ __launch_bounds__(128) void k_vert_align(const float* __restrict__ fT,
                                                    const float* __restrict__ verts,
                                                    unsigned* __restrict__ out,
                                                    int N, int H, int W) {
  int v = blockIdx.x;
  if (v >= N) return;
  int c = threadIdx.x;
  float vx = verts[(size_t)v * 3 + 0];
  float vy = verts[(size_t)v * 3 + 1];
  float fx = (vx + 1.f) * 0.5f * (float)(W - 1);
  float fy = (vy + 1.f) * 0.5f * (float)(H - 1);
  float x0f = floorf(fx), y0f = floorf(fy);
  float wx = fx - x0f, wy = fy - y0f;
  int x0 = (int)x0f, y0 = (int)y0f;
  float acc = 0.f;
#pragma unroll
  for (int dy = 0; dy < 2; ++dy) {
#pragma unroll
    for (int dx = 0; dx < 2; ++dx) {
      int yi = y0 + dy, xi = x0 + dx;
      bool valid = (yi >= 0) && (yi < H) && (xi >= 0) && (xi < W);
      int yc = min(max(yi, 0), H - 1);
      int xc = min(max(xi, 0), W - 1);
      float val = fT[((size_t)yc * W + xc) * 128 + c];
      float wgt = (dy ? wy : 1.f - wy) * (dx ? wx : 1.f - wx);
      acc += valid ? val * wgt : 0.f;
    }
  }
  out[(size_t)v * 128 + c] = pck(acc);
}

// G[v] = pack( sum_{u in adj(v)} rec(X[u]) )
template <int CH>
__global__ __launch_bounds__(256) void k_gather(const int* __restrict__ rowptr,
                                                const int* __restrict__ adj,
                                                const unsigned* __restrict__ X,
                                                unsigned* __restrict__ G, int N) {
  int idx = blockIdx.x * blockDim.x + threadIdx.x;
  int v = idx / (CH / 4);
  if (v >= N) return;
  int c = (idx % (CH / 4)) * 4;
  float a0 = 0.f, a1 = 0.f, a2 = 0.f, a3 = 0.f;
  int lo = rowptr[v], hi = rowptr[v + 1];
  for (int i = lo; i < hi; ++i) {
    uint4 h = *(const uint4*)(X + (size_t)adj[i] * CH + c);
    a0 += rec(h.x); a1 += rec(h.y); a2 += rec(h.z); a3 += rec(h.w);
  }
  uint4 o;
  o.x = pck(a0); o.y = pck(a1); o.z = pck(a2); o.w = pck(a3);
  *(uint4*)(G + (size_t)v * CH + c) = o;
}

// ---------------- packed-panel MFMA layer (128r x 64c tile) ----------------
// Y = concat_panels(X...) @ [W0;W1] + b0 + deg*b1 (split-bf16 3-term)
// All staging via global_load_lds; X LDS [128][16 chunks] with chunk^=(row&15);
// W LDS = SWZ image landed linearly from pre-swizzled tiles.
struct Panels {
  const unsigned* p[4];
  int ks[4];
  int ld[4];
};

#define SWZ(row, slot) (((row) * 64) + (((slot) ^ ((row) & 7)) * 8))

__device__ inline bf16x8 as_bf(uint4v v) {
  union { uint4v u; bf16x8 b; } x;
  x.u = v;
  return x.b;
}

__global__ __launch_bounds__(256) void k_layer(
    Panels pd, int Kmm,
    const unsigned short* __restrict__ w0h, const unsigned short* __restrict__ w0l,
    const unsigned short* __restrict__ w1h, const unsigned short* __restrict__ w1l,
    int Kw,
    const float* __restrict__ b0, const float* __restrict__ b1,
    const int* __restrict__ deg,
    unsigned* __restrict__ Y, int N) {
  __shared__ __attribute__((aligned(16))) unsigned X_lds[128 * 64];      // 32 KB
  __shared__ __attribute__((aligned(16))) unsigned short Wh_lds[4096];   // 8 KB
  __shared__ __attribute__((aligned(16))) unsigned short Wl_lds[4096];   // 8 KB
  int tid = threadIdx.x;
  int lane = tid & 63;
  int wid = tid >> 6;
  int wm = wid & 1, wn = wid >> 1;

  // XCD-aware swizzle: groups of 8 row-tiles x 4 col-blocks
  int nrt = (N + 127) >> 7;
  int total = nrt * 4;
  int flat = blockIdx.x;
  int rowtile, colblk;
  if ((flat & ~31) + 32 <= total) {
    int sub = flat & 31;
    rowtile = (flat >> 5) * 8 + (sub & 7);
    colblk = sub >> 3;
  } else {
    rowtile = flat >> 2;
    colblk = flat & 3;
  }
  int row0 = rowtile * 128;
  int col0 = colblk * 64;
  int nktbw = Kw >> 6;

  f32x4 acc[4][2];
#pragma unroll
  for (int m = 0; m < 4; ++m)
#pragma unroll
    for (int n = 0; n < 2; ++n) acc[m][n] = (f32x4){0.f, 0.f, 0.f, 0.f};

  for (int kt = 0; kt < Kmm; kt += 64) {
    // panel select (wave-uniform)
    int pi = (kt >= pd.ks[1]) + (kt >= pd.ks[2]) + (kt >= pd.ks[3]);
    const unsigned* base = pd.p[pi];
    int ld = pd.ld[pi];
    int koff = kt - pd.ks[pi];
    // ---- X stage: 32 wave-instrs; source pre-swizzled chunk = j ^ (row&15)
#pragma unroll
    for (int i = 0; i < 8; ++i) {
      int inst = wid * 8 + i;
      int row = inst * 4 + (lane >> 4);
      int j = lane & 15;
      int vc = min(row0 + row, N - 1);
      const unsigned* src = base + (size_t)vc * ld + koff + ((j ^ (row & 15)) << 2);
      GLOAD16(src, &X_lds[inst * 256]);
    }
    // ---- W stage: linear DMA of pre-swizzled tiles (8 KB per plane)
    const unsigned short* th;
    const unsigned short* tl;
    {
      int ktb = (kt < Kw) ? (kt >> 6) : ((kt - Kw) >> 6);
      const unsigned short* mh = (kt < Kw) ? w0h : w1h;
      const unsigned short* ml = (kt < Kw) ? w0l : w1l;
      size_t tb = ((size_t)(colblk * nktbw + ktb)) * 4096;
      th = mh + tb;
      tl = ml + tb;
    }
#pragma unroll
    for (int i = 0; i < 2; ++i) {
      int inst = wid * 2 + i;
      GLOAD16(th + inst * 512 + lane * 8, &Wh_lds[inst * 512]);
      GLOAD16(tl + inst * 512 + lane * 8, &Wl_lds[inst * 512]);
    }
    __syncthreads();
    // ---- compute
#pragma unroll
    for (int ks = 0; ks < 2; ++ks) {
      int slot = ks * 4 + (lane >> 4);
      bf16x8 ah[4], al[4];
#pragma unroll
      for (int m = 0; m < 4; ++m) {
        int row = wm * 64 + m * 16 + (lane & 15);
        int rx = row & 15;
        const unsigned* xp = X_lds + row * 64;
        uint4 u0 = *(const uint4*)(xp + (((2 * slot) ^ rx) << 2));
        uint4 u1 = *(const uint4*)(xp + (((2 * slot + 1) ^ rx) << 2));
        uint4v hv, lv;
        hv.x = __builtin_amdgcn_perm(u0.y, u0.x, 0x07060302u);
        hv.y = __builtin_amdgcn_perm(u0.w, u0.z, 0x07060302u);
        hv.z = __builtin_amdgcn_perm(u1.y, u1.x, 0x07060302u);
        hv.w = __builtin_amdgcn_perm(u1.w, u1.z, 0x07060302u);
        lv.x = __builtin_amdgcn_perm(u0.y, u0.x, 0x05040100u);
        lv.y = __builtin_amdgcn_perm(u0.w, u0.z, 0x05040100u);
        lv.z = __builtin_amdgcn_perm(u1.y, u1.x, 0x05040100u);
        lv.w = __builtin_amdgcn_perm(u1.w, u1.z, 0x05040100u);
        ah[m] = as_bf(hv);
        al[m] = as_bf(lv);
      }
      bf16x8 bh[2], bl[2];
#pragma unroll
      for (int n = 0; n < 2; ++n) {
        int nr = wn * 32 + n * 16 + (lane & 15);
        int wi = SWZ(nr, slot);
        bh[n] = *(const bf16x8*)&Wh_lds[wi];
        bl[n] = *(const bf16x8*)&Wl_lds[wi];
      }
#pragma unroll
      for (int m = 0; m < 4; ++m)
#pragma unroll
        for (int n = 0; n < 2; ++n) {
          f32x4 c = acc[m][n];
          c = __builtin_amdgcn_mfma_f32_16x16x32_bf16(al[m], bh[n], c, 0, 0, 0);
          c = __builtin_amdgcn_mfma_f32_16x16x32_bf16(ah[m], bl[n], c, 0, 0, 0);
          c = __builtin_amdgcn_mfma_f32_16x16x32_bf16(ah[m], bh[n], c, 0, 0, 0);
          acc[m][n] = c;
        }
    }
    __syncthreads();
  }

  // epilogue: pack( v + b0[col] + deg[row]*b1[col] )
#pragma unroll
  for (int m = 0; m < 4; ++m) {
    int rbase = row0 + wm * 64 + m * 16 + (lane >> 4) * 4;
    float dv[4];
#pragma unroll
    for (int r = 0; r < 4; ++r)
      dv[r] = (rbase + r < N) ? (float)deg[rbase + r] : 0.f;
#pragma unroll
    for (int n = 0; n < 2; ++n) {
      int col = col0 + wn * 32 + n * 16 + (lane & 15);
      float bb0 = b0[col], bb1 = b1[col];
      f32x4 v = acc[m][n];
#pragma unroll
      for (int r = 0; r < 4; ++r) {
        int row = rbase + r;
        if (row < N)
          Y[(size_t)row * HID + col] = pck(v[r] + bb0 + dv[r] * bb1);
      }
    }
  }
}

__global__ __launch_bounds__(256) void k_rowdot3(const unsigned* __restrict__ X,
                                                 const float* __restrict__ W,
                                                 const float* __restrict__ b,
                                                 float* __restrict__ Y, int N) {
  int gid = blockIdx.x * blockDim.x + threadIdx.x;
  int row = gid >> 6;
  int lane = threadIdx.x & 63;
  if (row >= N) return;
  uint4 xv = ((const uint4*)(X + (size_t)row * HID))[lane];
  float s0 = 0.f, s1 = 0.f, s2 = 0.f;
#pragma unroll
  for (int k = 0; k < 4; ++k) {
    float x = rec((&xv.x)[k]);
    int kk = lane * 4 + k;
    s0 += x * W[kk * 3 + 0];
    s1 += x * W[kk * 3 + 1];
    s2 += x * W[kk * 3 + 2];
  }
#pragma unroll
  for (int off = 32; off > 0; off >>= 1) {
    s0 += __shfl_down(s0, off);
    s1 += __shfl_down(s1, off);
    s2 += __shfl_down(s2, off);
  }
  if (lane == 0) {
    Y[(size_t)row * 3 + 0] = s0 + b[0];
    Y[(size_t)row * 3 + 1] = s1 + b[1];
    Y[(size_t)row * 3 + 2] = s2 + b[2];
  }
}

__global__ __launch_bounds__(256) void k_scatter3(const int* __restrict__ edges,
                                                  const float* __restrict__ H,
                                                  float* __restrict__ OUT, int E) {
  int e = blockIdx.x * blockDim.x + threadIdx.x;
  if (e >= E) return;
  int a = edges[(size_t)e * 2 + 0];
  int b = edges[(size_t)e * 2 + 1];
#pragma unroll
  for (int k = 0; k < 3; ++k) {
    atomicAdd(&OUT[(size_t)a * 3 + k], H[(size_t)b * 3 + k]);
    atomicAdd(&OUT[(size_t)b * 3 + k], H[(size_t)a * 3 + k]);
  }
}

__global__ __launch_bounds__(256) void k_subdiv3(const float* __restrict__ c,
                                                 const int* __restrict__ edges,
                                                 float* __restrict__ v, int N, int E) {
  int i = blockIdx.x * blockDim.x + threadIdx.x;
  if (i >= N + E) return;
  if (i < N) {
#pragma unroll
    for (int k = 0; k < 3; ++k) v[(size_t)i * 3 + k] = c[(size_t)i * 3 + k];
  } else {
    int e = i - N;
    int a = edges[(size_t)e * 2 + 0];
    int b = edges[(size_t)e * 2 + 1];
#pragma unroll
    for (int k = 0; k < 3; ++k)
      v[(size_t)i * 3 + k] = 0.5f * (c[(size_t)a * 3 + k] + c[(size_t)b * 3 + k]);
  }
}

__global__ __launch_bounds__(256) void k_subdiv_feat(const unsigned* __restrict__ x,
                                                     const int* __restrict__ edges,
                                                     unsigned* __restrict__ out, int N, int E) {
  int idx = blockIdx.x * blockDim.x + threadIdx.x;
  int v = idx >> 6;
  if (v >= N + E) return;
  int c = (threadIdx.x & 63) * 4;
  uint4 r;
  if (v < N) {
    r = *(const uint4*)(x + (size_t)v * HID + c);
  } else {
    int e = v - N;
    int a = edges[(size_t)e * 2 + 0];
    int b = edges[(size_t)e * 2 + 1];
    uint4 xa = *(const uint4*)(x + (size_t)a * HID + c);
    uint4 xb = *(const uint4*)(x + (size_t)b * HID + c);
    r.x = pck(0.5f * (rec(xa.x) + rec(xb.x)));
    r.y = pck(0.5f * (rec(xa.y) + rec(xb.y)));
    r.z = pck(0.5f * (rec(xa.z) + rec(xb.z)));
    r.w = pck(0.5f * (rec(xa.w) + rec(xb.w)));
  }
  *(uint4*)(out + (size_t)v * HID + c) = r;
}

// ---------------- launcher ----------------

extern "C" void kernel_launch(void* const* d_in, const int* in_sizes, int n_in,
                              void* d_out, int out_size, void* d_ws, size_t ws_size,
                              hipStream_t stream) {
  const float* conv64  = (const float*)d_in[0];
  const float* conv128 = (const float*)d_in[1];
  const float* conv256 = (const float*)d_in[2];
  const float* verts0  = (const float*)d_in[3];
  const int*   edges1  = (const int*)d_in[4];
  const int*   edges2  = (const int*)d_in[5];
  const int*   edges3  = (const int*)d_in[6];
  const float* w_in1 = (const float*)d_in[7],  *b_in1 = (const float*)d_in[8];
  const float* w_h1  = (const float*)d_in[9],  *b_h1  = (const float*)d_in[10];
  const float* w_out1= (const float*)d_in[11], *b_out1= (const float*)d_in[12];
  const float* w_in2 = (const float*)d_in[13], *b_in2 = (const float*)d_in[14];
  const float* w_h2  = (const float*)d_in[15], *b_h2  = (const float*)d_in[16];
  const float* w_out2= (const float*)d_in[17], *b_out2= (const float*)d_in[18];
  const float* w_in3 = (const float*)d_in[19], *b_in3 = (const float*)d_in[20];
  const float* w_h3  = (const float*)d_in[21], *b_h3  = (const float*)d_in[22];
  const float* w_out3= (const float*)d_in[23], *b_out3= (const float*)d_in[24];

  const int N1 = in_sizes[3] / 3;
  const int E1 = in_sizes[4] / 2;
  const int E2 = in_sizes[5] / 2;
  const int E3 = in_sizes[6] / 2;
  const int N2 = N1 + E1;
  const int N3 = N2 + E2;
  if ((size_t)N3 > MAXN3 || (size_t)E3 > MAXE3) return;

  unsigned *A, *B, *G, *D, *VA;
  float *C0, *C2, *Vv, *T;
  unsigned short *Wth, *Wtl;
  int *deg, *rowptr, *cursor, *adj;
  hipGetSymbolAddress((void**)&A,  HIP_SYMBOL(g_A));
  hipGetSymbolAddress((void**)&B,  HIP_SYMBOL(g_B));
  hipGetSymbolAddress((void**)&G,  HIP_SYMBOL(g_G));
  hipGetSymbolAddress((void**)&D,  HIP_SYMBOL(g_D));
  hipGetSymbolAddress((void**)&VA, HIP_SYMBOL(g_VA));
  hipGetSymbolAddress((void**)&C0, HIP_SYMBOL(g_C0));
  hipGetSymbolAddress((void**)&C2, HIP_SYMBOL(g_C2));
  hipGetSymbolAddress((void**)&Vv, HIP_SYMBOL(g_Vv));
  hipGetSymbolAddress((void**)&T,  HIP_SYMBOL(g_T));
  hipGetSymbolAddress((void**)&Wth, HIP_SYMBOL(g_Wth));
  hipGetSymbolAddress((void**)&Wtl, HIP_SYMBOL(g_Wtl));
  hipGetSymbolAddress((void**)&deg,    HIP_SYMBOL(g_deg));
  hipGetSymbolAddress((void**)&rowptr, HIP_SYMBOL(g_rowptr));
  hipGetSymbolAddress((void**)&cursor, HIP_SYMBOL(g_cursor));
  hipGetSymbolAddress((void**)&adj,    HIP_SYMBOL(g_adj));

  // ---- weight transpose + split + tile-swizzle (once per launch) ----
  k_wtrans<<<dim3(2, 4, 2),  256, 0, stream>>>(w_in1, Wth + OFF_IN1, Wtl + OFF_IN1, 128);
  k_wtrans<<<dim3(6, 4, 2),  256, 0, stream>>>(w_in2, Wth + OFF_IN2, Wtl + OFF_IN2, 384);
  k_wtrans<<<dim3(6, 4, 2),  256, 0, stream>>>(w_in3, Wth + OFF_IN3, Wtl + OFF_IN3, 384);
  k_wtrans<<<dim3(4, 4, 24), 256, 0, stream>>>(w_h1,  Wth + OFF_H1,  Wtl + OFF_H1,  256);
  k_wtrans<<<dim3(4, 4, 24), 256, 0, stream>>>(w_h2,  Wth + OFF_H2,  Wtl + OFF_H2,  256);
  k_wtrans<<<dim3(4, 4, 24), 256, 0, stream>>>(w_h3,  Wth + OFF_H3,  Wtl + OFF_H3,  256);

  const int BIG = 0x7fffffff;

  auto layerGrid = [](int N) { return dim3((unsigned)(((N + 127) / 128) * 4)); };

  auto build_csr = [&](const int* edges, int E, int N) {
    hipMemsetAsync(deg, 0, (size_t)N * sizeof(int), stream);
    k_count<<<(E + 255) / 256, 256, 0, stream>>>(edges, deg, E);
    k_scan<<<1, 1024, 0, stream>>>(deg, rowptr, cursor, N);
    k_fill<<<(E + 255) / 256, 256, 0, stream>>>(edges, cursor, adj, E);
  };

  auto gconv_hidden = [&](size_t offH, const float* bh, int N) {
    unsigned* X = A; unsigned* Y = B;
    for (int l = 0; l < 12; ++l) {
      const unsigned short* w0h = Wth + offH + (size_t)(2 * l + 0) * 65536;
      const unsigned short* w0l = Wtl + offH + (size_t)(2 * l + 0) * 65536;
      const unsigned short* w1h = Wth + offH + (size_t)(2 * l + 1) * 65536;
      const unsigned short* w1l = Wtl + offH + (size_t)(2 * l + 1) * 65536;
      const float* b0 = bh + (size_t)l * 2 * HID;
      const float* b1 = b0 + HID;
      k_gather<256><<<((size_t)N * 64 + 255) / 256, 256, 0, stream>>>(rowptr, adj, X, G, N);
      Panels pd = {{X, G, nullptr, nullptr}, {0, 256, BIG, BIG}, {256, 256, 0, 0}};
      k_layer<<<layerGrid(N), 256, 0, stream>>>(pd, 512, w0h, w0l, w1h, w1l, 256,
                                                b0, b1, deg, Y, N);
      std::swap(X, Y);
    }
    // x ends in A (12 swaps)
  };

  auto gconv_out = [&](const unsigned* X, const float* wo, const float* bo,
                       float* Cdst, const int* edges, int E, int N) {
    k_rowdot3<<<((size_t)N * 64 + 255) / 256, 256, 0, stream>>>(X, wo, bo, Cdst, N);
    k_rowdot3<<<((size_t)N * 64 + 255) / 256, 256, 0, stream>>>(X, wo + HID * 3, bo + 3, C2, N);
    k_scatter3<<<(E + 255) / 256, 256, 0, stream>>>(edges, C2, Cdst, E);
  };

  // ---------- Stage 1 ----------
  build_csr(edges1, E1, N1);
  k_transpose<<<56 * 56, 128, 0, stream>>>(conv64, T, 56 * 56);
  k_vert_align<<<N1, 128, 0, stream>>>(T, verts0, VA, N1, 56, 56);
  k_gather<128><<<((size_t)N1 * 32 + 255) / 256, 256, 0, stream>>>(rowptr, adj, VA, G, N1);
  {
    Panels pd = {{VA, G, nullptr, nullptr}, {0, 128, BIG, BIG}, {128, 128, 0, 0}};
    k_layer<<<layerGrid(N1), 256, 0, stream>>>(pd, 256,
        Wth + OFF_IN1, Wtl + OFF_IN1, Wth + OFF_IN1 + 32768, Wtl + OFF_IN1 + 32768, 128,
        b_in1, b_in1 + HID, deg, A, N1);
  }
  gconv_hidden(OFF_H1, b_h1, N1);                     // x -> A
  gconv_out(A, w_out1, b_out1, C0, edges1, E1, N1);   // c1 -> C0
  k_subdiv3<<<(N2 + 255) / 256, 256, 0, stream>>>(C0, edges1, Vv, N1, E1);                 // v2
  k_subdiv_feat<<<((size_t)N2 * 64 + 255) / 256, 256, 0, stream>>>(A, edges1, D, N1, E1);  // hs -> D

  // ---------- Stage 2 ----------
  build_csr(edges2, E2, N2);
  k_transpose<<<28 * 28, 128, 0, stream>>>(conv128, T, 28 * 28);
  k_vert_align<<<N2, 128, 0, stream>>>(T, Vv, VA, N2, 28, 28);
  k_gather<128><<<((size_t)N2 * 32 + 255) / 256, 256, 0, stream>>>(rowptr, adj, VA, G, N2);
  k_gather<256><<<((size_t)N2 * 64 + 255) / 256, 256, 0, stream>>>(rowptr, adj, D, B, N2);
  {
    const size_t m0 = OFF_IN2, m1 = OFF_IN2 + (size_t)256 * 384;
    Panels pd = {{VA, D, G, B}, {0, 128, 384, 512}, {128, 256, 128, 256}};
    k_layer<<<layerGrid(N2), 256, 0, stream>>>(pd, 768,
        Wth + m0, Wtl + m0, Wth + m1, Wtl + m1, 384,
        b_in2, b_in2 + HID, deg, A, N2);
  }
  gconv_hidden(OFF_H2, b_h2, N2);                     // x -> A
  gconv_out(A, w_out2, b_out2, C0, edges2, E2, N2);   // c2 -> C0
  k_subdiv3<<<(N3 + 255) / 256, 256, 0, stream>>>(C0, edges2, Vv, N2, E2);                 // v3
  k_subdiv_feat<<<((size_t)N3 * 64 + 255) / 256, 256, 0, stream>>>(A, edges2, D, N2, E2);  // hs -> D

  // ---------- Stage 3 ----------
  build_csr(edges3, E3, N3);
  k_transpose<<<14 * 14, 128, 0, stream>>>(conv256, T, 14 * 14);
  k_vert_align<<<N3, 128, 0, stream>>>(T, Vv, VA, N3, 14, 14);
  k_gather<128><<<((size_t)N3 * 32 + 255) / 256, 256, 0, stream>>>(rowptr, adj, VA, G, N3);
  k_gather<256><<<((size_t)N3 * 64 + 255) / 256, 256, 0, stream>>>(rowptr, adj, D, B, N3);
  {
    const size_t m0 = OFF_IN3, m1 = OFF_IN3 + (size_t)256 * 384;
    Panels pd = {{VA, D, G, B}, {0, 128, 384, 512}, {128, 256, 128, 256}};
    k_layer<<<layerGrid(N3), 256, 0, stream>>>(pd, 768,
        Wth + m0, Wtl + m0, Wth + m1, Wtl + m1, 384,
        b_in3, b_in3 + HID, deg, A, N3);
  }
  gconv_hidden(OFF_H3, b_h3, N3);                     // x -> A
  float* OUT = (float*)d_out;
  k_rowdot3<<<((size_t)N3 * 64 + 255) / 256, 256, 0, stream>>>(A, w_out3, b_out3, OUT, N3);
  k_rowdot3<<<((size_t)N3 * 64 + 255) / 256, 256, 0, stream>>>(A, w_out3 + HID * 3, b_out3 + 3, C2, N3);
  k_scatter3<<<(E3 + 255) / 256, 256, 0, stream>>>(edges3, C2, OUT, E3);
}

// Round 8
// 4577.306 us; speedup vs baseline: 1.8909x; 1.0638x over previous
//
#include <hip/hip_runtime.h>
#include <utility>

#define HID 256

typedef __attribute__((ext_vector_type(8))) short bf16x8;
typedef __attribute__((ext_vector_type(4))) float f32x4;
typedef __attribute__((ext_vector_type(4))) unsigned short us4;
typedef __attribute__((ext_vector_type(4))) unsigned uint4v;

// Topology constants for GRID_N=80
constexpr size_t MAXN3 = 100489;
constexpr size_t MAXE3 = 300200;

// Tiled-weight offsets (elements). Per matrix: [4 cb][K/64 ktb][4096 bf16],
// tile content pre-swizzled so a LINEAR global_load_lds produces the SWZ image.
constexpr size_t OFF_IN1 = 0;                       // 2 mats K=128
constexpr size_t OFF_IN2 = OFF_IN1 + 2 * 256 * 128; // 2 mats K=384
constexpr size_t OFF_IN3 = OFF_IN2 + 2 * 256 * 384;
constexpr size_t OFF_H1  = OFF_IN3 + 2 * 256 * 384; // 24 mats K=256
constexpr size_t OFF_H2  = OFF_H1 + 24 * 256 * 256;
constexpr size_t OFF_H3  = OFF_H2 + 24 * 256 * 256;
constexpr size_t WT_TOTAL = OFF_H3 + 24 * 256 * 256;

// Static device scratch (BSS — graph-capture safe). Feature buffers hold
// PACKED hi/lo bf16 pairs in one u32 (hi in top half): x == rec(u) exactly.
__device__ __attribute__((aligned(16))) unsigned g_A [MAXN3 * 256];
__device__ __attribute__((aligned(16))) unsigned g_B [MAXN3 * 256];
__device__ __attribute__((aligned(16))) unsigned g_G [MAXN3 * 256];
__device__ __attribute__((aligned(16))) unsigned g_D [MAXN3 * 256];
__device__ __attribute__((aligned(16))) unsigned g_VA[MAXN3 * 128];
__device__ float g_C0[MAXN3 * 3];
__device__ float g_C2[MAXN3 * 3];
__device__ float g_Vv[MAXN3 * 3];
__device__ float g_T [56 * 56 * 128];
__device__ __attribute__((aligned(16))) unsigned short g_Wth[WT_TOTAL];
__device__ __attribute__((aligned(16))) unsigned short g_Wtl[WT_TOTAL];
// CSR scratch
__device__ int g_deg   [MAXN3];
__device__ int g_rowptr[MAXN3 + 1];
__device__ int g_cursor[MAXN3];
__device__ int g_adj   [2 * MAXE3];
__device__ int g_bsum  [128];

__device__ inline float rec(unsigned u) {
  return __uint_as_float(u & 0xffff0000u) + __uint_as_float(u << 16);
}
__device__ inline unsigned pck(float f) {
  unsigned u = __float_as_uint(f);
  unsigned hi = u & 0xffff0000u;
  unsigned lo = __float_as_uint(f - __uint_as_float(hi)) >> 16;
  return hi | (lo & 0xffffu);
}

#define GLOAD16(g, l)                                                       \
  __builtin_amdgcn_global_load_lds(                                        \
      (const __attribute__((address_space(1))) unsigned*)(g),              \
      (__attribute__((address_space(3))) unsigned*)(l), 16, 0, 0)

// ---------------- weight transpose + split + tile-swizzle ----------------
// Out tile chunk c (n=c>>3, sp=c&7) holds W^T[cb*64+n][ktb*64+(sp^(n&7))*8 .. +7]
__global__ __launch_bounds__(256) void k_wtrans(const float* __restrict__ W,
                                                unsigned short* __restrict__ Oh,
                                                unsigned short* __restrict__ Ol,
                                                int K) {
  __shared__ float Ls[64][65];
  int ktb = blockIdx.x, cb = blockIdx.y, mat = blockIdx.z;
  int nktb = gridDim.x;
  const float* Wm = W + (size_t)mat * K * 256;
  int t = threadIdx.x;
#pragma unroll
  for (int i = 0; i < 16; ++i) {
    int idx = i * 256 + t;
    int kk = idx >> 6, cc = idx & 63;
    Ls[kk][cc] = Wm[(size_t)(ktb * 64 + kk) * 256 + cb * 64 + cc];
  }
  __syncthreads();
  size_t tb = ((size_t)(mat * 4 + cb) * nktb + ktb) * 4096;
#pragma unroll
  for (int i = 0; i < 2; ++i) {
    int c = t * 2 + i;
    int n = c >> 3, sp = c & 7;
    int kbase = (sp ^ (n & 7)) * 8;
    unsigned short hb[8], lb[8];
#pragma unroll
    for (int j = 0; j < 8; ++j) {
      float v = Ls[kbase + j][n];
      unsigned u = __float_as_uint(v);
      unsigned short hi = (unsigned short)(u >> 16);
      float hf = __uint_as_float(u & 0xffff0000u);
      hb[j] = hi;
      lb[j] = (unsigned short)(__float_as_uint(v - hf) >> 16);
    }
    *(us4*)(Oh + tb + c * 8)     = (us4){hb[0], hb[1], hb[2], hb[3]};
    *(us4*)(Oh + tb + c * 8 + 4) = (us4){hb[4], hb[5], hb[6], hb[7]};
    *(us4*)(Ol + tb + c * 8)     = (us4){lb[0], lb[1], lb[2], lb[3]};
    *(us4*)(Ol + tb + c * 8 + 4) = (us4){lb[4], lb[5], lb[6], lb[7]};
  }
}

// ---------------- CSR build (parallel scan) ----------------

__global__ __launch_bounds__(256) void k_count(const int* __restrict__ edges,
                                               int* __restrict__ deg, int E) {
  int e = blockIdx.x * blockDim.x + threadIdx.x;
  if (e >= E) return;
  atomicAdd(&deg[edges[2 * e + 0]], 1);
  atomicAdd(&deg[edges[2 * e + 1]], 1);
}

__global__ __launch_bounds__(256) void k_scan_part(const int* __restrict__ deg,
                                                   int* __restrict__ bsum, int N) {
  __shared__ int s[256];
  int t = threadIdx.x;
  int base = blockIdx.x * 1024 + t * 4;
  int v = 0;
#pragma unroll
  for (int i = 0; i < 4; ++i) {
    int idx = base + i;
    if (idx < N) v += deg[idx];
  }
  s[t] = v;
  __syncthreads();
  for (int off = 128; off > 0; off >>= 1) {
    if (t < off) s[t] += s[t + off];
    __syncthreads();
  }
  if (t == 0) bsum[blockIdx.x] = s[0];
}

__global__ __launch_bounds__(128) void k_scan_top(int* __restrict__ bsum, int nb) {
  __shared__ int s[128];
  int t = threadIdx.x;
  s[t] = (t < nb) ? bsum[t] : 0;
  __syncthreads();
  for (int off = 1; off < 128; off <<= 1) {
    int v = (t >= off) ? s[t - off] : 0;
    __syncthreads();
    s[t] += v;
    __syncthreads();
  }
  if (t < nb) bsum[t] = (t == 0) ? 0 : s[t - 1];
}

__global__ __launch_bounds__(256) void k_scan_write(const int* __restrict__ deg,
                                                    const int* __restrict__ bsum,
                                                    int* __restrict__ rowptr,
                                                    int* __restrict__ cursor, int N) {
  __shared__ int s[256];
  int t = threadIdx.x;
  int base = blockIdx.x * 1024;
  int d[4];
  int local = 0;
#pragma unroll
  for (int i = 0; i < 4; ++i) {
    int idx = base + t * 4 + i;
    d[i] = (idx < N) ? deg[idx] : 0;
    local += d[i];
  }
  s[t] = local;
  __syncthreads();
  for (int off = 1; off < 256; off <<= 1) {
    int v = (t >= off) ? s[t - off] : 0;
    __syncthreads();
    s[t] += v;
    __syncthreads();
  }
  int run = bsum[blockIdx.x] + s[t] - local;
#pragma unroll
  for (int i = 0; i < 4; ++i) {
    int idx = base + t * 4 + i;
    if (idx < N) {
      rowptr[idx] = run;
      cursor[idx] = run;
    }
    run += d[i];
  }
  if (blockIdx.x == gridDim.x - 1 && t == 255) rowptr[N] = run;
}

__global__ __launch_bounds__(256) void k_fill(const int* __restrict__ edges,
                                              int* __restrict__ cursor,
                                              int* __restrict__ adj, int E) {
  int e = blockIdx.x * blockDim.x + threadIdx.x;
  if (e >= E) return;
  int a = edges[2 * e + 0];
  int b = edges[2 * e + 1];
  adj[atomicAdd(&cursor[a], 1)] = b;
  adj[atomicAdd(&cursor[b], 1)] = a;
}

// ---------------- misc kernels ----------------

__global__ __launch_bounds__(128) void k_transpose(const float* __restrict__ in,
                                                   float* __restrict__ out, int HW) {
  int p = blockIdx.x;
  int c = threadIdx.x;
  if (p < HW) out[(size_t)p * 128 + c] = in[(size_t)c * HW + p];
}

__global__ __launch_bounds__(128) void k_vert_align(const float* __restrict__ fT,
                                                    const float* __restrict__ verts,
                                                    unsigned* __restrict__ out,
                                                    int N, int H, int W) {
  int v = blockIdx.x;
  if (v >= N) return;
  int c = threadIdx.x;
  float vx = verts[(size_t)v * 3 + 0];
  float vy = verts[(size_t)v * 3 + 1];
  float fx = (vx + 1.f) * 0.5f * (float)(W - 1);
  float fy = (vy + 1.f) * 0.5f * (float)(H - 1);
  float x0f = floorf(fx), y0f = floorf(fy);
  float wx = fx - x0f, wy = fy - y0f;
  int x0 = (int)x0f, y0 = (int)y0f;
  float acc = 0.f;
#pragma unroll
  for (int dy = 0; dy < 2; ++dy) {
#pragma unroll
    for (int dx = 0; dx < 2; ++dx) {
      int yi = y0 + dy, xi = x0 + dx;
      bool valid = (yi >= 0) && (yi < H) && (xi >= 0) && (xi < W);
      int yc = min(max(yi, 0), H - 1);
      int xc = min(max(xi, 0), W - 1);
      float val = fT[((size_t)yc * W + xc) * 128 + c];
      float wgt = (dy ? wy : 1.f - wy) * (dx ? wx : 1.f - wx);
      acc += valid ? val * wgt : 0.f;
    }
  }
  out[(size_t)v * 128 + c] = pck(acc);
}

// G[v] = pack( sum_{u in adj(v)} rec(X[u]) )
template <int CH>
__global__ __launch_bounds__(256) void k_gather(const int* __restrict__ rowptr,
                                                const int* __restrict__ adj,
                                                const unsigned* __restrict__ X,
                                                unsigned* __restrict__ G, int N) {
  int idx = blockIdx.x * blockDim.x + threadIdx.x;
  int v = idx / (CH / 4);
  if (v >= N) return;
  int c = (idx % (CH / 4)) * 4;
  float a0 = 0.f, a1 = 0.f, a2 = 0.f, a3 = 0.f;
  int lo = rowptr[v], hi = rowptr[v + 1];
  for (int i = lo; i < hi; ++i) {
    uint4 h = *(const uint4*)(X + (size_t)adj[i] * CH + c);
    a0 += rec(h.x); a1 += rec(h.y); a2 += rec(h.z); a3 += rec(h.w);
  }
  uint4 o;
  o.x = pck(a0); o.y = pck(a1); o.z = pck(a2); o.w = pck(a3);
  *(uint4*)(G + (size_t)v * CH + c) = o;
}

// ---------------- packed-panel MFMA layer (128r x 64c tile) ----------------
struct Panels {
  const unsigned* p[4];
  int ks[4];
  int ld[4];
};

#define SWZ(row, slot) (((row) * 64) + (((slot) ^ ((row) & 7)) * 8))

__device__ inline bf16x8 as_bf(uint4v v) {
  union { uint4v u; bf16x8 b; } x;
  x.u = v;
  return x.b;
}

__global__ __launch_bounds__(256) void k_layer(
    Panels pd, int Kmm,
    const unsigned short* __restrict__ w0h, const unsigned short* __restrict__ w0l,
    const unsigned short* __restrict__ w1h, const unsigned short* __restrict__ w1l,
    int Kw,
    const float* __restrict__ b0, const float* __restrict__ b1,
    const int* __restrict__ deg,
    unsigned* __restrict__ Y, int N) {
  __shared__ __attribute__((aligned(16))) unsigned X_lds[128 * 64];      // 32 KB
  __shared__ __attribute__((aligned(16))) unsigned short Wh_lds[4096];   // 8 KB
  __shared__ __attribute__((aligned(16))) unsigned short Wl_lds[4096];   // 8 KB
  int tid = threadIdx.x;
  int lane = tid & 63;
  int wid = tid >> 6;
  int wm = wid & 1, wn = wid >> 1;

  int nrt = (N + 127) >> 7;
  int total = nrt * 4;
  int flat = blockIdx.x;
  int rowtile, colblk;
  if ((flat & ~31) + 32 <= total) {
    int sub = flat & 31;
    rowtile = (flat >> 5) * 8 + (sub & 7);
    colblk = sub >> 3;
  } else {
    rowtile = flat >> 2;
    colblk = flat & 3;
  }
  int row0 = rowtile * 128;
  int col0 = colblk * 64;
  int nktbw = Kw >> 6;

  f32x4 acc[4][2];
#pragma unroll
  for (int m = 0; m < 4; ++m)
#pragma unroll
    for (int n = 0; n < 2; ++n) acc[m][n] = (f32x4){0.f, 0.f, 0.f, 0.f};

  for (int kt = 0; kt < Kmm; kt += 64) {
    int pi = (kt >= pd.ks[1]) + (kt >= pd.ks[2]) + (kt >= pd.ks[3]);
    const unsigned* base = pd.p[pi];
    int ld = pd.ld[pi];
    int koff = kt - pd.ks[pi];
#pragma unroll
    for (int i = 0; i < 8; ++i) {
      int inst = wid * 8 + i;
      int row = inst * 4 + (lane >> 4);
      int j = lane & 15;
      int vc = min(row0 + row, N - 1);
      const unsigned* src = base + (size_t)vc * ld + koff + ((j ^ (row & 15)) << 2);
      GLOAD16(src, &X_lds[inst * 256]);
    }
    const unsigned short* th;
    const unsigned short* tl;
    {
      int ktb = (kt < Kw) ? (kt >> 6) : ((kt - Kw) >> 6);
      const unsigned short* mh = (kt < Kw) ? w0h : w1h;
      const unsigned short* ml = (kt < Kw) ? w0l : w1l;
      size_t tb = ((size_t)(colblk * nktbw + ktb)) * 4096;
      th = mh + tb;
      tl = ml + tb;
    }
#pragma unroll
    for (int i = 0; i < 2; ++i) {
      int inst = wid * 2 + i;
      GLOAD16(th + inst * 512 + lane * 8, &Wh_lds[inst * 512]);
      GLOAD16(tl + inst * 512 + lane * 8, &Wl_lds[inst * 512]);
    }
    __syncthreads();
#pragma unroll
    for (int ks = 0; ks < 2; ++ks) {
      int slot = ks * 4 + (lane >> 4);
      bf16x8 ah[4], al[4];
#pragma unroll
      for (int m = 0; m < 4; ++m) {
        int row = wm * 64 + m * 16 + (lane & 15);
        int rx = row & 15;
        const unsigned* xp = X_lds + row * 64;
        uint4 u0 = *(const uint4*)(xp + (((2 * slot) ^ rx) << 2));
        uint4 u1 = *(const uint4*)(xp + (((2 * slot + 1) ^ rx) << 2));
        uint4v hv, lv;
        hv.x = __builtin_amdgcn_perm(u0.y, u0.x, 0x07060302u);
        hv.y = __builtin_amdgcn_perm(u0.w, u0.z, 0x07060302u);
        hv.z = __builtin_amdgcn_perm(u1.y, u1.x, 0x07060302u);
        hv.w = __builtin_amdgcn_perm(u1.w, u1.z, 0x07060302u);
        lv.x = __builtin_amdgcn_perm(u0.y, u0.x, 0x05040100u);
        lv.y = __builtin_amdgcn_perm(u0.w, u0.z, 0x05040100u);
        lv.z = __builtin_amdgcn_perm(u1.y, u1.x, 0x05040100u);
        lv.w = __builtin_amdgcn_perm(u1.w, u1.z, 0x05040100u);
        ah[m] = as_bf(hv);
        al[m] = as_bf(lv);
      }
      bf16x8 bh[2], bl[2];
#pragma unroll
      for (int n = 0; n < 2; ++n) {
        int nr = wn * 32 + n * 16 + (lane & 15);
        int wi = SWZ(nr, slot);
        bh[n] = *(const bf16x8*)&Wh_lds[wi];
        bl[n] = *(const bf16x8*)&Wl_lds[wi];
      }
#pragma unroll
      for (int m = 0; m < 4; ++m)
#pragma unroll
        for (int n = 0; n < 2; ++n) {
          f32x4 c = acc[m][n];
          c = __builtin_amdgcn_mfma_f32_16x16x32_bf16(al[m], bh[n], c, 0, 0, 0);
          c = __builtin_amdgcn_mfma_f32_16x16x32_bf16(ah[m], bl[n], c, 0, 0, 0);
          c = __builtin_amdgcn_mfma_f32_16x16x32_bf16(ah[m], bh[n], c, 0, 0, 0);
          acc[m][n] = c;
        }
    }
    __syncthreads();
  }

#pragma unroll
  for (int m = 0; m < 4; ++m) {
    int rbase = row0 + wm * 64 + m * 16 + (lane >> 4) * 4;
    float dv[4];
#pragma unroll
    for (int r = 0; r < 4; ++r)
      dv[r] = (rbase + r < N) ? (float)deg[rbase + r] : 0.f;
#pragma unroll
    for (int n = 0; n < 2; ++n) {
      int col = col0 + wn * 32 + n * 16 + (lane & 15);
      float bb0 = b0[col], bb1 = b1[col];
      f32x4 v = acc[m][n];
#pragma unroll
      for (int r = 0; r < 4; ++r) {
        int row = rbase + r;
        if (row < N)
          Y[(size_t)row * HID + col] = pck(v[r] + bb0 + dv[r] * bb1);
      }
    }
  }
}

// Both 256x3 output heads in one X pass.
__global__ __launch_bounds__(256) void k_rowdot6(const unsigned* __restrict__ X,
                                                 const float* __restrict__ W,
                                                 const float* __restrict__ b,
                                                 float* __restrict__ Y0,
                                                 float* __restrict__ Y1, int N) {
  int gid = blockIdx.x * blockDim.x + threadIdx.x;
  int row = gid >> 6;
  int lane = threadIdx.x & 63;
  if (row >= N) return;
  uint4 xv = ((const uint4*)(X + (size_t)row * HID))[lane];
  float s[6] = {0.f, 0.f, 0.f, 0.f, 0.f, 0.f};
#pragma unroll
  for (int k = 0; k < 4; ++k) {
    float x = rec((&xv.x)[k]);
    int kk = lane * 4 + k;
#pragma unroll
    for (int j = 0; j < 3; ++j) {
      s[j]     += x * W[kk * 3 + j];
      s[3 + j] += x * W[768 + kk * 3 + j];
    }
  }
#pragma unroll
  for (int off = 32; off > 0; off >>= 1)
#pragma unroll
    for (int j = 0; j < 6; ++j) s[j] += __shfl_down(s[j], off);
  if (lane == 0) {
#pragma unroll
    for (int j = 0; j < 3; ++j) {
      Y0[(size_t)row * 3 + j] = s[j] + b[j];
      Y1[(size_t)row * 3 + j] = s[3 + j] + b[3 + j];
    }
  }
}

__global__ __launch_bounds__(256) void k_scatter3(const int* __restrict__ edges,
                                                  const float* __restrict__ H,
                                                  float* __restrict__ OUT, int E) {
  int e = blockIdx.x * blockDim.x + threadIdx.x;
  if (e >= E) return;
  int a = edges[(size_t)e * 2 + 0];
  int b = edges[(size_t)e * 2 + 1];
#pragma unroll
  for (int k = 0; k < 3; ++k) {
    atomicAdd(&OUT[(size_t)a * 3 + k], H[(size_t)b * 3 + k]);
    atomicAdd(&OUT[(size_t)b * 3 + k], H[(size_t)a * 3 + k]);
  }
}

__global__ __launch_bounds__(256) void k_subdiv3(const float* __restrict__ c,
                                                 const int* __restrict__ edges,
                                                 float* __restrict__ v, int N, int E) {
  int i = blockIdx.x * blockDim.x + threadIdx.x;
  if (i >= N + E) return;
  if (i < N) {
#pragma unroll
    for (int k = 0; k < 3; ++k) v[(size_t)i * 3 + k] = c[(size_t)i * 3 + k];
  } else {
    int e = i - N;
    int a = edges[(size_t)e * 2 + 0];
    int b = edges[(size_t)e * 2 + 1];
#pragma unroll
    for (int k = 0; k < 3; ++k)
      v[(size_t)i * 3 + k] = 0.5f * (c[(size_t)a * 3 + k] + c[(size_t)b * 3 + k]);
  }
}

__global__ __launch_bounds__(256) void k_subdiv_feat(const unsigned* __restrict__ x,
                                                     const int* __restrict__ edges,
                                                     unsigned* __restrict__ out, int N, int E) {
  int idx = blockIdx.x * blockDim.x + threadIdx.x;
  int v = idx >> 6;
  if (v >= N + E) return;
  int c = (threadIdx.x & 63) * 4;
  uint4 r;
  if (v < N) {
    r = *(const uint4*)(x + (size_t)v * HID + c);
  } else {
    int e = v - N;
    int a = edges[(size_t)e * 2 + 0];
    int b = edges[(size_t)e * 2 + 1];
    uint4 xa = *(const uint4*)(x + (size_t)a * HID + c);
    uint4 xb = *(const uint4*)(x + (size_t)b * HID + c);
    r.x = pck(0.5f * (rec(xa.x) + rec(xb.x)));
    r.y = pck(0.5f * (rec(xa.y) + rec(xb.y)));
    r.z = pck(0.5f * (rec(xa.z) + rec(xb.z)));
    r.w = pck(0.5f * (rec(xa.w) + rec(xb.w)));
  }
  *(uint4*)(out + (size_t)v * HID + c) = r;
}

// ---------------- launcher ----------------

extern "C" void kernel_launch(void* const* d_in, const int* in_sizes, int n_in,
                              void* d_out, int out_size, void* d_ws, size_t ws_size,
                              hipStream_t stream) {
  const float* conv64  = (const float*)d_in[0];
  const float* conv128 = (const float*)d_in[1];
  const float* conv256 = (const float*)d_in[2];
  const float* verts0  = (const float*)d_in[3];
  const int*   edges1  = (const int*)d_in[4];
  const int*   edges2  = (const int*)d_in[5];
  const int*   edges3  = (const int*)d_in[6];
  const float* w_in1 = (const float*)d_in[7],  *b_in1 = (const float*)d_in[8];
  const float* w_h1  = (const float*)d_in[9],  *b_h1  = (const float*)d_in[10];
  const float* w_out1= (const float*)d_in[11], *b_out1= (const float*)d_in[12];
  const float* w_in2 = (const float*)d_in[13], *b_in2 = (const float*)d_in[14];
  const float* w_h2  = (const float*)d_in[15], *b_h2  = (const float*)d_in[16];
  const float* w_out2= (const float*)d_in[17], *b_out2= (const float*)d_in[18];
  const float* w_in3 = (const float*)d_in[19], *b_in3 = (const float*)d_in[20];
  const float* w_h3  = (const float*)d_in[21], *b_h3  = (const float*)d_in[22];
  const float* w_out3= (const float*)d_in[23], *b_out3= (const float*)d_in[24];

  const int N1 = in_sizes[3] / 3;
  const int E1 = in_sizes[4] / 2;
  const int E2 = in_sizes[5] / 2;
  const int E3 = in_sizes[6] / 2;
  const int N2 = N1 + E1;
  const int N3 = N2 + E2;
  if ((size_t)N3 > MAXN3 || (size_t)E3 > MAXE3) return;

  unsigned *A, *B, *G, *D, *VA;
  float *C0, *C2, *Vv, *T;
  unsigned short *Wth, *Wtl;
  int *deg, *rowptr, *cursor, *adj, *bsum;
  hipGetSymbolAddress((void**)&A,  HIP_SYMBOL(g_A));
  hipGetSymbolAddress((void**)&B,  HIP_SYMBOL(g_B));
  hipGetSymbolAddress((void**)&G,  HIP_SYMBOL(g_G));
  hipGetSymbolAddress((void**)&D,  HIP_SYMBOL(g_D));
  hipGetSymbolAddress((void**)&VA, HIP_SYMBOL(g_VA));
  hipGetSymbolAddress((void**)&C0, HIP_SYMBOL(g_C0));
  hipGetSymbolAddress((void**)&C2, HIP_SYMBOL(g_C2));
  hipGetSymbolAddress((void**)&Vv, HIP_SYMBOL(g_Vv));
  hipGetSymbolAddress((void**)&T,  HIP_SYMBOL(g_T));
  hipGetSymbolAddress((void**)&Wth, HIP_SYMBOL(g_Wth));
  hipGetSymbolAddress((void**)&Wtl, HIP_SYMBOL(g_Wtl));
  hipGetSymbolAddress((void**)&deg,    HIP_SYMBOL(g_deg));
  hipGetSymbolAddress((void**)&rowptr, HIP_SYMBOL(g_rowptr));
  hipGetSymbolAddress((void**)&cursor, HIP_SYMBOL(g_cursor));
  hipGetSymbolAddress((void**)&adj,    HIP_SYMBOL(g_adj));
  hipGetSymbolAddress((void**)&bsum,   HIP_SYMBOL(g_bsum));

  // ---- weight transpose + split + tile-swizzle (once per launch) ----
  k_wtrans<<<dim3(2, 4, 2),  256, 0, stream>>>(w_in1, Wth + OFF_IN1, Wtl + OFF_IN1, 128);
  k_wtrans<<<dim3(6, 4, 2),  256, 0, stream>>>(w_in2, Wth + OFF_IN2, Wtl + OFF_IN2, 384);
  k_wtrans<<<dim3(6, 4, 2),  256, 0, stream>>>(w_in3, Wth + OFF_IN3, Wtl + OFF_IN3, 384);
  k_wtrans<<<dim3(4, 4, 24), 256, 0, stream>>>(w_h1,  Wth + OFF_H1,  Wtl + OFF_H1,  256);
  k_wtrans<<<dim3(4, 4, 24), 256, 0, stream>>>(w_h2,  Wth + OFF_H2,  Wtl + OFF_H2,  256);
  k_wtrans<<<dim3(4, 4, 24), 256, 0, stream>>>(w_h3,  Wth + OFF_H3,  Wtl + OFF_H3,  256);

  const int BIG = 0x7fffffff;

  auto layerGrid = [](int N) { return dim3((unsigned)(((N + 127) / 128) * 4)); };

  auto build_csr = [&](const int* edges, int E, int N) {
    hipMemsetAsync(deg, 0, (size_t)N * sizeof(int), stream);
    k_count<<<(E + 255) / 256, 256, 0, stream>>>(edges, deg, E);
    int nb = (N + 1023) / 1024;
    k_scan_part<<<nb, 256, 0, stream>>>(deg, bsum, N);
    k_scan_top<<<1, 128, 0, stream>>>(bsum, nb);
    k_scan_write<<<nb, 256, 0, stream>>>(deg, bsum, rowptr, cursor, N);
    k_fill<<<(E + 255) / 256, 256, 0, stream>>>(edges, cursor, adj, E);
  };

  auto gconv_hidden = [&](size_t offH, const float* bh, int N) {
    unsigned* X = A; unsigned* Y = B;
    for (int l = 0; l < 12; ++l) {
      const unsigned short* w0h = Wth + offH + (size_t)(2 * l + 0) * 65536;
      const unsigned short* w0l = Wtl + offH + (size_t)(2 * l + 0) * 65536;
      const unsigned short* w1h = Wth + offH + (size_t)(2 * l + 1) * 65536;
      const unsigned short* w1l = Wtl + offH + (size_t)(2 * l + 1) * 65536;
      const float* b0 = bh + (size_t)l * 2 * HID;
      const float* b1 = b0 + HID;
      k_gather<256><<<((size_t)N * 64 + 255) / 256, 256, 0, stream>>>(rowptr, adj, X, G, N);
      Panels pd = {{X, G, nullptr, nullptr}, {0, 256, BIG, BIG}, {256, 256, 0, 0}};
      k_layer<<<layerGrid(N), 256, 0, stream>>>(pd, 512, w0h, w0l, w1h, w1l, 256,
                                                b0, b1, deg, Y, N);
      std::swap(X, Y);
    }
    // x ends in A (12 swaps)
  };

  auto gconv_out = [&](const unsigned* X, const float* wo, const float* bo,
                       float* Cdst, const int* edges, int E, int N) {
    k_rowdot6<<<((size_t)N * 64 + 255) / 256, 256, 0, stream>>>(X, wo, bo, Cdst, C2, N);
    k_scatter3<<<(E + 255) / 256, 256, 0, stream>>>(edges, C2, Cdst, E);
  };

  // ---------- Stage 1 ----------
  build_csr(edges1, E1, N1);
  k_transpose<<<56 * 56, 128, 0, stream>>>(conv64, T, 56 * 56);
  k_vert_align<<<N1, 128, 0, stream>>>(T, verts0, VA, N1, 56, 56);
  k_gather<128><<<((size_t)N1 * 32 + 255) / 256, 256, 0, stream>>>(rowptr, adj, VA, G, N1);
  {
    Panels pd = {{VA, G, nullptr, nullptr}, {0, 128, BIG, BIG}, {128, 128, 0, 0}};
    k_layer<<<layerGrid(N1), 256, 0, stream>>>(pd, 256,
        Wth + OFF_IN1, Wtl + OFF_IN1, Wth + OFF_IN1 + 32768, Wtl + OFF_IN1 + 32768, 128,
        b_in1, b_in1 + HID, deg, A, N1);
  }
  gconv_hidden(OFF_H1, b_h1, N1);                     // x -> A
  gconv_out(A, w_out1, b_out1, C0, edges1, E1, N1);   // c1 -> C0
  k_subdiv3<<<(N2 + 255) / 256, 256, 0, stream>>>(C0, edges1, Vv, N1, E1);                 // v2
  k_subdiv_feat<<<((size_t)N2 * 64 + 255) / 256, 256, 0, stream>>>(A, edges1, D, N1, E1);  // hs -> D

  // ---------- Stage 2 ----------
  build_csr(edges2, E2, N2);
  k_transpose<<<28 * 28, 128, 0, stream>>>(conv128, T, 28 * 28);
  k_vert_align<<<N2, 128, 0, stream>>>(T, Vv, VA, N2, 28, 28);
  k_gather<128><<<((size_t)N2 * 32 + 255) / 256, 256, 0, stream>>>(rowptr, adj, VA, G, N2);
  k_gather<256><<<((size_t)N2 * 64 + 255) / 256, 256, 0, stream>>>(rowptr, adj, D, B, N2);
  {
    const size_t m0 = OFF_IN2, m1 = OFF_IN2 + (size_t)256 * 384;
    Panels pd = {{VA, D, G, B}, {0, 128, 384, 512}, {128, 256, 128, 256}};
    k_layer<<<layerGrid(N2), 256, 0, stream>>>(pd, 768,
        Wth + m0, Wtl + m0, Wth + m1, Wtl + m1, 384,
        b_in2, b_in2 + HID, deg, A, N2);
  }
  gconv_hidden(OFF_H2, b_h2, N2);                     // x -> A
  gconv_out(A, w_out2, b_out2, C0, edges2, E2, N2);   // c2 -> C0
  k_subdiv3<<<(N3 + 255) / 256, 256, 0, stream>>>(C0, edges2, Vv, N2, E2);                 // v3
  k_subdiv_feat<<<((size_t)N3 * 64 + 255) / 256, 256, 0, stream>>>(A, edges2, D, N2, E2);  // hs -> D

  // ---------- Stage 3 ----------
  build_csr(edges3, E3, N3);
  k_transpose<<<14 * 14, 128, 0, stream>>>(conv256, T, 14 * 14);
  k_vert_align<<<N3, 128, 0, stream>>>(T, Vv, VA, N3, 14, 14);
  k_gather<128><<<((size_t)N3 * 32 + 255) / 256, 256, 0, stream>>>(rowptr, adj, VA, G, N3);
  k_gather<256><<<((size_t)N3 * 64 + 255) / 256, 256, 0, stream>>>(rowptr, adj, D, B, N3);
  {
    const size_t m0 = OFF_IN3, m1 = OFF_IN3 + (size_t)256 * 384;
    Panels pd = {{VA, D, G, B}, {0, 128, 384, 512}, {128, 256, 128, 256}};
    k_layer<<<layerGrid(N3), 256, 0, stream>>>(pd, 768,
        Wth + m0, Wtl + m0, Wth + m1, Wtl + m1, 384,
        b_in3, b_in3 + HID, deg, A, N3);
  }
  gconv_hidden(OFF_H3, b_h3, N3);                     // x -> A
  float* OUT = (float*)d_out;
  k_rowdot6<<<((size_t)N3 * 64 + 255) / 256, 256, 0, stream>>>(A, w_out3, b_out3, OUT, C2, N3);
  k_scatter3<<<(E3 + 255) / 256, 256, 0, stream>>>(edges3, C2, OUT, E3);
}

// Round 9
// 4220.988 us; speedup vs baseline: 2.0505x; 1.0844x over previous
//
#include <hip/hip_runtime.h>
#include <utility>

#define HID 256

typedef __attribute__((ext_vector_type(8))) short bf16x8;
typedef __attribute__((ext_vector_type(4))) float f32x4;
typedef __attribute__((ext_vector_type(4))) unsigned short us4;
typedef __attribute__((ext_vector_type(8))) unsigned short us8;

// Topology constants for GRID_N=80
constexpr size_t MAXN3 = 100489;
constexpr size_t MAXE3 = 300200;

// Tiled-weight offsets (elements). Per matrix: [4 cb][K/64 ktb][4096 bf16],
// tile content pre-swizzled so a LINEAR global_load_lds produces the swizzled image.
constexpr size_t OFF_IN1 = 0;                       // 2 mats K=128
constexpr size_t OFF_IN2 = OFF_IN1 + 2 * 256 * 128; // 2 mats K=384
constexpr size_t OFF_IN3 = OFF_IN2 + 2 * 256 * 384;
constexpr size_t OFF_H1  = OFF_IN3 + 2 * 256 * 384; // 24 mats K=256
constexpr size_t OFF_H2  = OFF_H1 + 24 * 256 * 256;
constexpr size_t OFF_H3  = OFF_H2 + 24 * 256 * 256;
constexpr size_t WT_TOTAL = OFF_H3 + 24 * 256 * 256;

// Static device scratch (BSS — graph-capture safe). Features = split bf16
// hi/lo PLANES: x == b2f(hi) + b2f(lo) exactly as the old packed format.
__device__ __attribute__((aligned(16))) unsigned short g_Ah[MAXN3 * 256];
__device__ __attribute__((aligned(16))) unsigned short g_Al[MAXN3 * 256];
__device__ __attribute__((aligned(16))) unsigned short g_Bh[MAXN3 * 256];
__device__ __attribute__((aligned(16))) unsigned short g_Bl[MAXN3 * 256];
__device__ __attribute__((aligned(16))) unsigned short g_Gh[MAXN3 * 256];
__device__ __attribute__((aligned(16))) unsigned short g_Gl[MAXN3 * 256];
__device__ __attribute__((aligned(16))) unsigned short g_Dh[MAXN3 * 256];
__device__ __attribute__((aligned(16))) unsigned short g_Dl[MAXN3 * 256];
__device__ __attribute__((aligned(16))) unsigned short g_VAh[MAXN3 * 128];
__device__ __attribute__((aligned(16))) unsigned short g_VAl[MAXN3 * 128];
__device__ float g_C0[MAXN3 * 3];
__device__ float g_C2[MAXN3 * 3];
__device__ float g_Vv[MAXN3 * 3];
__device__ float g_T [56 * 56 * 128];
__device__ __attribute__((aligned(16))) unsigned short g_Wth[WT_TOTAL];
__device__ __attribute__((aligned(16))) unsigned short g_Wtl[WT_TOTAL];
// CSR scratch
__device__ int g_deg   [MAXN3];
__device__ int g_rowptr[MAXN3 + 1];
__device__ int g_cursor[MAXN3];
__device__ int g_adj   [2 * MAXE3];
__device__ int g_bsum  [128];

__device__ inline float b2f(unsigned short h) {
  return __uint_as_float((unsigned)h << 16);
}
__device__ inline void fsplit(float f, unsigned short& h, unsigned short& l) {
  unsigned u = __float_as_uint(f);
  h = (unsigned short)(u >> 16);
  float hf = __uint_as_float(u & 0xffff0000u);
  l = (unsigned short)(__float_as_uint(f - hf) >> 16);
}

#define GLOAD16(g, l)                                                       \
  __builtin_amdgcn_global_load_lds(                                        \
      (const __attribute__((address_space(1))) unsigned*)(const void*)(g), \
      (__attribute__((address_space(3))) unsigned*)(void*)(l), 16, 0, 0)

// ---------------- weight transpose + split + tile-swizzle ----------------
// Out tile chunk c (n=c>>3, sp=c&7) holds W^T[cb*64+n][ktb*64+(sp^(n&7))*8 .. +7]
__global__ __launch_bounds__(256) void k_wtrans(const float* __restrict__ W,
                                                unsigned short* __restrict__ Oh,
                                                unsigned short* __restrict__ Ol,
                                                int K) {
  __shared__ float Ls[64][65];
  int ktb = blockIdx.x, cb = blockIdx.y, mat = blockIdx.z;
  int nktb = gridDim.x;
  const float* Wm = W + (size_t)mat * K * 256;
  int t = threadIdx.x;
#pragma unroll
  for (int i = 0; i < 16; ++i) {
    int idx = i * 256 + t;
    int kk = idx >> 6, cc = idx & 63;
    Ls[kk][cc] = Wm[(size_t)(ktb * 64 + kk) * 256 + cb * 64 + cc];
  }
  __syncthreads();
  size_t tb = ((size_t)(mat * 4 + cb) * nktb + ktb) * 4096;
#pragma unroll
  for (int i = 0; i < 2; ++i) {
    int c = t * 2 + i;
    int n = c >> 3, sp = c & 7;
    int kbase = (sp ^ (n & 7)) * 8;
    unsigned short hb[8], lb[8];
#pragma unroll
    for (int j = 0; j < 8; ++j) {
      float v = Ls[kbase + j][n];
      unsigned short hi, lo;
      fsplit(v, hi, lo);
      hb[j] = hi;
      lb[j] = lo;
    }
    *(us4*)(Oh + tb + c * 8)     = (us4){hb[0], hb[1], hb[2], hb[3]};
    *(us4*)(Oh + tb + c * 8 + 4) = (us4){hb[4], hb[5], hb[6], hb[7]};
    *(us4*)(Ol + tb + c * 8)     = (us4){lb[0], lb[1], lb[2], lb[3]};
    *(us4*)(Ol + tb + c * 8 + 4) = (us4){lb[4], lb[5], lb[6], lb[7]};
  }
}

// ---------------- CSR build (parallel scan) ----------------

__global__ __launch_bounds__(256) void k_count(const int* __restrict__ edges,
                                               int* __restrict__ deg, int E) {
  int e = blockIdx.x * blockDim.x + threadIdx.x;
  if (e >= E) return;
  atomicAdd(&deg[edges[2 * e + 0]], 1);
  atomicAdd(&deg[edges[2 * e + 1]], 1);
}

__global__ __launch_bounds__(256) void k_scan_part(const int* __restrict__ deg,
                                                   int* __restrict__ bsum, int N) {
  __shared__ int s[256];
  int t = threadIdx.x;
  int base = blockIdx.x * 1024 + t * 4;
  int v = 0;
#pragma unroll
  for (int i = 0; i < 4; ++i) {
    int idx = base + i;
    if (idx < N) v += deg[idx];
  }
  s[t] = v;
  __syncthreads();
  for (int off = 128; off > 0; off >>= 1) {
    if (t < off) s[t] += s[t + off];
    __syncthreads();
  }
  if (t == 0) bsum[blockIdx.x] = s[0];
}

__global__ __launch_bounds__(128) void k_scan_top(int* __restrict__ bsum, int nb) {
  __shared__ int s[128];
  int t = threadIdx.x;
  s[t] = (t < nb) ? bsum[t] : 0;
  __syncthreads();
  for (int off = 1; off < 128; off <<= 1) {
    int v = (t >= off) ? s[t - off] : 0;
    __syncthreads();
    s[t] += v;
    __syncthreads();
  }
  if (t < nb) bsum[t] = (t == 0) ? 0 : s[t - 1];
}

__global__ __launch_bounds__(256) void k_scan_write(const int* __restrict__ deg,
                                                    const int* __restrict__ bsum,
                                                    int* __restrict__ rowptr,
                                                    int* __restrict__ cursor, int N) {
  __shared__ int s[256];
  int t = threadIdx.x;
  int base = blockIdx.x * 1024;
  int d[4];
  int local = 0;
#pragma unroll
  for (int i = 0; i < 4; ++i) {
    int idx = base + t * 4 + i;
    d[i] = (idx < N) ? deg[idx] : 0;
    local += d[i];
  }
  s[t] = local;
  __syncthreads();
  for (int off = 1; off < 256; off <<= 1) {
    int v = (t >= off) ? s[t - off] : 0;
    __syncthreads();
    s[t] += v;
    __syncthreads();
  }
  int run = bsum[blockIdx.x] + s[t] - local;
#pragma unroll
  for (int i = 0; i < 4; ++i) {
    int idx = base + t * 4 + i;
    if (idx < N) {
      rowptr[idx] = run;
      cursor[idx] = run;
    }
    run += d[i];
  }
  if (blockIdx.x == gridDim.x - 1 && t == 255) rowptr[N] = run;
}

__global__ __launch_bounds__(256) void k_fill(const int* __restrict__ edges,
                                              int* __restrict__ cursor,
                                              int* __restrict__ adj, int E) {
  int e = blockIdx.x * blockDim.x + threadIdx.x;
  if (e >= E) return;
  int a = edges[2 * e + 0];
  int b = edges[2 * e + 1];
  adj[atomicAdd(&cursor[a], 1)] = b;
  adj[atomicAdd(&cursor[b], 1)] = a;
}

// ---------------- misc kernels ----------------

__global__ __launch_bounds__(128) void k_transpose(const float* __restrict__ in,
                                                   float* __restrict__ out, int HW) {
  int p = blockIdx.x;
  int c = threadIdx.x;
  if (p < HW) out[(size_t)p * 128 + c] = in[(size_t)c * HW + p];
}

__global__ __launch_bounds__(128) void k_vert_align(const float* __restrict__ fT,
                                                    const float* __restrict__ verts,
                                                    unsigned short* __restrict__ oh,
                                                    unsigned short* __restrict__ ol,
                                                    int N, int H, int W) {
  int v = blockIdx.x;
  if (v >= N) return;
  int c = threadIdx.x;
  float vx = verts[(size_t)v * 3 + 0];
  float vy = verts[(size_t)v * 3 + 1];
  float fx = (vx + 1.f) * 0.5f * (float)(W - 1);
  float fy = (vy + 1.f) * 0.5f * (float)(H - 1);
  float x0f = floorf(fx), y0f = floorf(fy);
  float wx = fx - x0f, wy = fy - y0f;
  int x0 = (int)x0f, y0 = (int)y0f;
  float acc = 0.f;
#pragma unroll
  for (int dy = 0; dy < 2; ++dy) {
#pragma unroll
    for (int dx = 0; dx < 2; ++dx) {
      int yi = y0 + dy, xi = x0 + dx;
      bool valid = (yi >= 0) && (yi < H) && (xi >= 0) && (xi < W);
      int yc = min(max(yi, 0), H - 1);
      int xc = min(max(xi, 0), W - 1);
      float val = fT[((size_t)yc * W + xc) * 128 + c];
      float wgt = (dy ? wy : 1.f - wy) * (dx ? wx : 1.f - wx);
      acc += valid ? val * wgt : 0.f;
    }
  }
  unsigned short h, l;
  fsplit(acc, h, l);
  oh[(size_t)v * 128 + c] = h;
  ol[(size_t)v * 128 + c] = l;
}

// G[v] = split( sum_{u in adj(v)} (b2f(Xh[u]) + b2f(Xl[u])) ), 8 ch/thread
template <int CH>
__global__ __launch_bounds__(256) void k_gather(const int* __restrict__ rowptr,
                                                const int* __restrict__ adj,
                                                const unsigned short* __restrict__ Xh,
                                                const unsigned short* __restrict__ Xl,
                                                unsigned short* __restrict__ Gh,
                                                unsigned short* __restrict__ Gl, int N) {
  constexpr int TPV = CH / 8;
  int idx = blockIdx.x * blockDim.x + threadIdx.x;
  int v = idx / TPV;
  if (v >= N) return;
  int c = (idx % TPV) * 8;
  float a[8] = {};
  int lo = rowptr[v], hi = rowptr[v + 1];
  for (int i = lo; i < hi; ++i) {
    size_t base = (size_t)adj[i] * CH + c;
    us8 h = *(const us8*)(Xh + base);
    us8 l = *(const us8*)(Xl + base);
#pragma unroll
    for (int j = 0; j < 8; ++j) a[j] += b2f(h[j]) + b2f(l[j]);
  }
  us8 oh, ol;
#pragma unroll
  for (int j = 0; j < 8; ++j) {
    unsigned short hh, ll;
    fsplit(a[j], hh, ll);
    oh[j] = hh;
    ol[j] = ll;
  }
  *(us8*)(Gh + (size_t)v * CH + c) = oh;
  *(us8*)(Gl + (size_t)v * CH + c) = ol;
}

// ---------------- split-plane MFMA layer (128r x 64c tile) ----------------
struct Panels {
  const unsigned short* ph[4];
  const unsigned short* pl[4];
  int ks[4];
  int ld[4];
};

// involution swizzle: LDS[row][s] holds source chunk s^(row&7); 8-bf16 chunks
#define SWZ(row, slot) (((row) * 64) + (((slot) ^ ((row) & 7)) << 3))

__global__ __launch_bounds__(256) void k_layer(
    Panels pd, int Kmm,
    const unsigned short* __restrict__ w0h, const unsigned short* __restrict__ w0l,
    const unsigned short* __restrict__ w1h, const unsigned short* __restrict__ w1l,
    int Kw,
    const float* __restrict__ b0, const float* __restrict__ b1,
    const int* __restrict__ deg,
    unsigned short* __restrict__ Yh, unsigned short* __restrict__ Yl, int N) {
  __shared__ __attribute__((aligned(16))) unsigned short Xh_lds[128 * 64]; // 16 KB
  __shared__ __attribute__((aligned(16))) unsigned short Xl_lds[128 * 64]; // 16 KB
  __shared__ __attribute__((aligned(16))) unsigned short Wh_lds[4096];     // 8 KB
  __shared__ __attribute__((aligned(16))) unsigned short Wl_lds[4096];     // 8 KB
  int tid = threadIdx.x;
  int lane = tid & 63;
  int wid = tid >> 6;
  int wm = wid & 1, wn = wid >> 1;

  // XCD-aware swizzle: groups of 8 row-tiles x 4 col-blocks
  int nrt = (N + 127) >> 7;
  int total = nrt * 4;
  int flat = blockIdx.x;
  int rowtile, colblk;
  if ((flat & ~31) + 32 <= total) {
    int sub = flat & 31;
    rowtile = (flat >> 5) * 8 + (sub & 7);
    colblk = sub >> 3;
  } else {
    rowtile = flat >> 2;
    colblk = flat & 3;
  }
  int row0 = rowtile * 128;
  int col0 = colblk * 64;
  int nktbw = Kw >> 6;

  f32x4 acc[4][2];
#pragma unroll
  for (int m = 0; m < 4; ++m)
#pragma unroll
    for (int n = 0; n < 2; ++n) acc[m][n] = (f32x4){0.f, 0.f, 0.f, 0.f};

  for (int kt = 0; kt < Kmm; kt += 64) {
    int pi = (kt >= pd.ks[1]) + (kt >= pd.ks[2]) + (kt >= pd.ks[3]);
    const unsigned short* bph = pd.ph[pi];
    const unsigned short* bpl = pd.pl[pi];
    int ld = pd.ld[pi];
    int koff = kt - pd.ks[pi];
    // ---- X stage: 1024 16B-chunks per plane; chunk c: row=c>>3, slot=c&7;
    //      source pre-swizzled chunk = slot ^ (row&7); LDS linear.
#pragma unroll
    for (int i = 0; i < 4; ++i) {
      int c = (wid * 4 + i) * 64 + lane;
      int row = c >> 3, slot = c & 7;
      int vg = min(row0 + row, N - 1);
      size_t srcoff = (size_t)vg * ld + koff + ((slot ^ (row & 7)) << 3);
      GLOAD16(bph + srcoff, &Xh_lds[(size_t)c * 8]);
      GLOAD16(bpl + srcoff, &Xl_lds[(size_t)c * 8]);
    }
    // ---- W stage: linear DMA of pre-swizzled tiles
    const unsigned short* th;
    const unsigned short* tl;
    {
      int ktb = (kt < Kw) ? (kt >> 6) : ((kt - Kw) >> 6);
      const unsigned short* mh = (kt < Kw) ? w0h : w1h;
      const unsigned short* ml = (kt < Kw) ? w0l : w1l;
      size_t tb = ((size_t)(colblk * nktbw + ktb)) * 4096;
      th = mh + tb;
      tl = ml + tb;
    }
#pragma unroll
    for (int i = 0; i < 2; ++i) {
      int inst = wid * 2 + i;
      GLOAD16(th + inst * 512 + lane * 8, &Wh_lds[inst * 512]);
      GLOAD16(tl + inst * 512 + lane * 8, &Wl_lds[inst * 512]);
    }
    __syncthreads();
    // ---- compute: direct ds_read_b128 -> MFMA, zero repack
#pragma unroll
    for (int ks = 0; ks < 2; ++ks) {
      int slot = ks * 4 + (lane >> 4);
      bf16x8 ah[4], al[4];
#pragma unroll
      for (int m = 0; m < 4; ++m) {
        int row = wm * 64 + m * 16 + (lane & 15);
        int off = SWZ(row, slot);
        ah[m] = *(const bf16x8*)&Xh_lds[off];
        al[m] = *(const bf16x8*)&Xl_lds[off];
      }
      bf16x8 bh[2], bl[2];
#pragma unroll
      for (int n = 0; n < 2; ++n) {
        int nr = wn * 32 + n * 16 + (lane & 15);
        int wi = SWZ(nr, slot);
        bh[n] = *(const bf16x8*)&Wh_lds[wi];
        bl[n] = *(const bf16x8*)&Wl_lds[wi];
      }
#pragma unroll
      for (int m = 0; m < 4; ++m)
#pragma unroll
        for (int n = 0; n < 2; ++n) {
          f32x4 c = acc[m][n];
          c = __builtin_amdgcn_mfma_f32_16x16x32_bf16(al[m], bh[n], c, 0, 0, 0);
          c = __builtin_amdgcn_mfma_f32_16x16x32_bf16(ah[m], bl[n], c, 0, 0, 0);
          c = __builtin_amdgcn_mfma_f32_16x16x32_bf16(ah[m], bh[n], c, 0, 0, 0);
          acc[m][n] = c;
        }
    }
    __syncthreads();
  }

  // epilogue: split( v + b0[col] + deg[row]*b1[col] ) into hi/lo planes
#pragma unroll
  for (int m = 0; m < 4; ++m) {
    int rbase = row0 + wm * 64 + m * 16 + (lane >> 4) * 4;
    float dv[4];
#pragma unroll
    for (int r = 0; r < 4; ++r)
      dv[r] = (rbase + r < N) ? (float)deg[rbase + r] : 0.f;
#pragma unroll
    for (int n = 0; n < 2; ++n) {
      int col = col0 + wn * 32 + n * 16 + (lane & 15);
      float bb0 = b0[col], bb1 = b1[col];
      f32x4 v = acc[m][n];
#pragma unroll
      for (int r = 0; r < 4; ++r) {
        int row = rbase + r;
        if (row < N) {
          unsigned short h, l;
          fsplit(v[r] + bb0 + dv[r] * bb1, h, l);
          Yh[(size_t)row * HID + col] = h;
          Yl[(size_t)row * HID + col] = l;
        }
      }
    }
  }
}

// Both 256x3 output heads in one X pass.
__global__ __launch_bounds__(256) void k_rowdot6(const unsigned short* __restrict__ Xh,
                                                 const unsigned short* __restrict__ Xl,
                                                 const float* __restrict__ W,
                                                 const float* __restrict__ b,
                                                 float* __restrict__ Y0,
                                                 float* __restrict__ Y1, int N) {
  int gid = blockIdx.x * blockDim.x + threadIdx.x;
  int row = gid >> 6;
  int lane = threadIdx.x & 63;
  if (row >= N) return;
  size_t base = (size_t)row * HID + lane * 4;
  us4 hv = *(const us4*)(Xh + base);
  us4 lv = *(const us4*)(Xl + base);
  float s[6] = {0.f, 0.f, 0.f, 0.f, 0.f, 0.f};
#pragma unroll
  for (int k = 0; k < 4; ++k) {
    float x = b2f(hv[k]) + b2f(lv[k]);
    int kk = lane * 4 + k;
#pragma unroll
    for (int j = 0; j < 3; ++j) {
      s[j]     += x * W[kk * 3 + j];
      s[3 + j] += x * W[768 + kk * 3 + j];
    }
  }
#pragma unroll
  for (int off = 32; off > 0; off >>= 1)
#pragma unroll
    for (int j = 0; j < 6; ++j) s[j] += __shfl_down(s[j], off);
  if (lane == 0) {
#pragma unroll
    for (int j = 0; j < 3; ++j) {
      Y0[(size_t)row * 3 + j] = s[j] + b[j];
      Y1[(size_t)row * 3 + j] = s[3 + j] + b[3 + j];
    }
  }
}

__global__ __launch_bounds__(256) void k_scatter3(const int* __restrict__ edges,
                                                  const float* __restrict__ H,
                                                  float* __restrict__ OUT, int E) {
  int e = blockIdx.x * blockDim.x + threadIdx.x;
  if (e >= E) return;
  int a = edges[(size_t)e * 2 + 0];
  int b = edges[(size_t)e * 2 + 1];
#pragma unroll
  for (int k = 0; k < 3; ++k) {
    atomicAdd(&OUT[(size_t)a * 3 + k], H[(size_t)b * 3 + k]);
    atomicAdd(&OUT[(size_t)b * 3 + k], H[(size_t)a * 3 + k]);
  }
}

__global__ __launch_bounds__(256) void k_subdiv3(const float* __restrict__ c,
                                                 const int* __restrict__ edges,
                                                 float* __restrict__ v, int N, int E) {
  int i = blockIdx.x * blockDim.x + threadIdx.x;
  if (i >= N + E) return;
  if (i < N) {
#pragma unroll
    for (int k = 0; k < 3; ++k) v[(size_t)i * 3 + k] = c[(size_t)i * 3 + k];
  } else {
    int e = i - N;
    int a = edges[(size_t)e * 2 + 0];
    int b = edges[(size_t)e * 2 + 1];
#pragma unroll
    for (int k = 0; k < 3; ++k)
      v[(size_t)i * 3 + k] = 0.5f * (c[(size_t)a * 3 + k] + c[(size_t)b * 3 + k]);
  }
}

// hs = subdiv(x): 8 channels/thread on hi/lo planes
__global__ __launch_bounds__(256) void k_subdiv_feat(const unsigned short* __restrict__ xh,
                                                     const unsigned short* __restrict__ xl,
                                                     const int* __restrict__ edges,
                                                     unsigned short* __restrict__ oh,
                                                     unsigned short* __restrict__ ol,
                                                     int N, int E) {
  int idx = blockIdx.x * blockDim.x + threadIdx.x;
  int v = idx >> 5;
  if (v >= N + E) return;
  int c = (idx & 31) * 8;
  us8 rh, rl;
  if (v < N) {
    rh = *(const us8*)(xh + (size_t)v * HID + c);
    rl = *(const us8*)(xl + (size_t)v * HID + c);
  } else {
    int e = v - N;
    int a = edges[(size_t)e * 2 + 0];
    int b = edges[(size_t)e * 2 + 1];
    us8 ahv = *(const us8*)(xh + (size_t)a * HID + c);
    us8 alv = *(const us8*)(xl + (size_t)a * HID + c);
    us8 bhv = *(const us8*)(xh + (size_t)b * HID + c);
    us8 blv = *(const us8*)(xl + (size_t)b * HID + c);
#pragma unroll
    for (int j = 0; j < 8; ++j) {
      float f = 0.5f * ((b2f(ahv[j]) + b2f(alv[j])) + (b2f(bhv[j]) + b2f(blv[j])));
      unsigned short hh, ll;
      fsplit(f, hh, ll);
      rh[j] = hh;
      rl[j] = ll;
    }
  }
  *(us8*)(oh + (size_t)v * HID + c) = rh;
  *(us8*)(ol + (size_t)v * HID + c) = rl;
}

// ---------------- launcher ----------------

extern "C" void kernel_launch(void* const* d_in, const int* in_sizes, int n_in,
                              void* d_out, int out_size, void* d_ws, size_t ws_size,
                              hipStream_t stream) {
  const float* conv64  = (const float*)d_in[0];
  const float* conv128 = (const float*)d_in[1];
  const float* conv256 = (const float*)d_in[2];
  const float* verts0  = (const float*)d_in[3];
  const int*   edges1  = (const int*)d_in[4];
  const int*   edges2  = (const int*)d_in[5];
  const int*   edges3  = (const int*)d_in[6];
  const float* w_in1 = (const float*)d_in[7],  *b_in1 = (const float*)d_in[8];
  const float* w_h1  = (const float*)d_in[9],  *b_h1  = (const float*)d_in[10];
  const float* w_out1= (const float*)d_in[11], *b_out1= (const float*)d_in[12];
  const float* w_in2 = (const float*)d_in[13], *b_in2 = (const float*)d_in[14];
  const float* w_h2  = (const float*)d_in[15], *b_h2  = (const float*)d_in[16];
  const float* w_out2= (const float*)d_in[17], *b_out2= (const float*)d_in[18];
  const float* w_in3 = (const float*)d_in[19], *b_in3 = (const float*)d_in[20];
  const float* w_h3  = (const float*)d_in[21], *b_h3  = (const float*)d_in[22];
  const float* w_out3= (const float*)d_in[23], *b_out3= (const float*)d_in[24];

  const int N1 = in_sizes[3] / 3;
  const int E1 = in_sizes[4] / 2;
  const int E2 = in_sizes[5] / 2;
  const int E3 = in_sizes[6] / 2;
  const int N2 = N1 + E1;
  const int N3 = N2 + E2;
  if ((size_t)N3 > MAXN3 || (size_t)E3 > MAXE3) return;

  unsigned short *Ah, *Al, *Bh, *Bl, *Gh, *Gl, *Dh, *Dl, *VAh, *VAl;
  float *C0, *C2, *Vv, *T;
  unsigned short *Wth, *Wtl;
  int *deg, *rowptr, *cursor, *adj, *bsum;
  hipGetSymbolAddress((void**)&Ah,  HIP_SYMBOL(g_Ah));
  hipGetSymbolAddress((void**)&Al,  HIP_SYMBOL(g_Al));
  hipGetSymbolAddress((void**)&Bh,  HIP_SYMBOL(g_Bh));
  hipGetSymbolAddress((void**)&Bl,  HIP_SYMBOL(g_Bl));
  hipGetSymbolAddress((void**)&Gh,  HIP_SYMBOL(g_Gh));
  hipGetSymbolAddress((void**)&Gl,  HIP_SYMBOL(g_Gl));
  hipGetSymbolAddress((void**)&Dh,  HIP_SYMBOL(g_Dh));
  hipGetSymbolAddress((void**)&Dl,  HIP_SYMBOL(g_Dl));
  hipGetSymbolAddress((void**)&VAh, HIP_SYMBOL(g_VAh));
  hipGetSymbolAddress((void**)&VAl, HIP_SYMBOL(g_VAl));
  hipGetSymbolAddress((void**)&C0, HIP_SYMBOL(g_C0));
  hipGetSymbolAddress((void**)&C2, HIP_SYMBOL(g_C2));
  hipGetSymbolAddress((void**)&Vv, HIP_SYMBOL(g_Vv));
  hipGetSymbolAddress((void**)&T,  HIP_SYMBOL(g_T));
  hipGetSymbolAddress((void**)&Wth, HIP_SYMBOL(g_Wth));
  hipGetSymbolAddress((void**)&Wtl, HIP_SYMBOL(g_Wtl));
  hipGetSymbolAddress((void**)&deg,    HIP_SYMBOL(g_deg));
  hipGetSymbolAddress((void**)&rowptr, HIP_SYMBOL(g_rowptr));
  hipGetSymbolAddress((void**)&cursor, HIP_SYMBOL(g_cursor));
  hipGetSymbolAddress((void**)&adj,    HIP_SYMBOL(g_adj));
  hipGetSymbolAddress((void**)&bsum,   HIP_SYMBOL(g_bsum));

  // ---- weight transpose + split + tile-swizzle (once per launch) ----
  k_wtrans<<<dim3(2, 4, 2),  256, 0, stream>>>(w_in1, Wth + OFF_IN1, Wtl + OFF_IN1, 128);
  k_wtrans<<<dim3(6, 4, 2),  256, 0, stream>>>(w_in2, Wth + OFF_IN2, Wtl + OFF_IN2, 384);
  k_wtrans<<<dim3(6, 4, 2),  256, 0, stream>>>(w_in3, Wth + OFF_IN3, Wtl + OFF_IN3, 384);
  k_wtrans<<<dim3(4, 4, 24), 256, 0, stream>>>(w_h1,  Wth + OFF_H1,  Wtl + OFF_H1,  256);
  k_wtrans<<<dim3(4, 4, 24), 256, 0, stream>>>(w_h2,  Wth + OFF_H2,  Wtl + OFF_H2,  256);
  k_wtrans<<<dim3(4, 4, 24), 256, 0, stream>>>(w_h3,  Wth + OFF_H3,  Wtl + OFF_H3,  256);

  const int BIG = 0x7fffffff;

  auto layerGrid = [](int N) { return dim3((unsigned)(((N + 127) / 128) * 4)); };

  auto build_csr = [&](const int* edges, int E, int N) {
    hipMemsetAsync(deg, 0, (size_t)N * sizeof(int), stream);
    k_count<<<(E + 255) / 256, 256, 0, stream>>>(edges, deg, E);
    int nb = (N + 1023) / 1024;
    k_scan_part<<<nb, 256, 0, stream>>>(deg, bsum, N);
    k_scan_top<<<1, 128, 0, stream>>>(bsum, nb);
    k_scan_write<<<nb, 256, 0, stream>>>(deg, bsum, rowptr, cursor, N);
    k_fill<<<(E + 255) / 256, 256, 0, stream>>>(edges, cursor, adj, E);
  };

  auto gconv_hidden = [&](size_t offH, const float* bh, int N) {
    unsigned short *Xh = Ah, *Xl = Al, *Yh = Bh, *Yl = Bl;
    for (int l = 0; l < 12; ++l) {
      const unsigned short* w0h = Wth + offH + (size_t)(2 * l + 0) * 65536;
      const unsigned short* w0l = Wtl + offH + (size_t)(2 * l + 0) * 65536;
      const unsigned short* w1h = Wth + offH + (size_t)(2 * l + 1) * 65536;
      const unsigned short* w1l = Wtl + offH + (size_t)(2 * l + 1) * 65536;
      const float* b0 = bh + (size_t)l * 2 * HID;
      const float* b1 = b0 + HID;
      k_gather<256><<<((size_t)N * 32 + 255) / 256, 256, 0, stream>>>(
          rowptr, adj, Xh, Xl, Gh, Gl, N);
      Panels pd = {{Xh, Gh, nullptr, nullptr}, {Xl, Gl, nullptr, nullptr},
                   {0, 256, BIG, BIG}, {256, 256, 0, 0}};
      k_layer<<<layerGrid(N), 256, 0, stream>>>(pd, 512, w0h, w0l, w1h, w1l, 256,
                                                b0, b1, deg, Yh, Yl, N);
      std::swap(Xh, Yh);
      std::swap(Xl, Yl);
    }
    // x ends in A planes (12 swaps)
  };

  auto gconv_out = [&](const unsigned short* Xh, const unsigned short* Xl,
                       const float* wo, const float* bo,
                       float* Cdst, const int* edges, int E, int N) {
    k_rowdot6<<<((size_t)N * 64 + 255) / 256, 256, 0, stream>>>(Xh, Xl, wo, bo, Cdst, C2, N);
    k_scatter3<<<(E + 255) / 256, 256, 0, stream>>>(edges, C2, Cdst, E);
  };

  // ---------- Stage 1 ----------
  build_csr(edges1, E1, N1);
  k_transpose<<<56 * 56, 128, 0, stream>>>(conv64, T, 56 * 56);
  k_vert_align<<<N1, 128, 0, stream>>>(T, verts0, VAh, VAl, N1, 56, 56);
  k_gather<128><<<((size_t)N1 * 16 + 255) / 256, 256, 0, stream>>>(
      rowptr, adj, VAh, VAl, Gh, Gl, N1);
  {
    Panels pd = {{VAh, Gh, nullptr, nullptr}, {VAl, Gl, nullptr, nullptr},
                 {0, 128, BIG, BIG}, {128, 128, 0, 0}};
    k_layer<<<layerGrid(N1), 256, 0, stream>>>(pd, 256,
        Wth + OFF_IN1, Wtl + OFF_IN1, Wth + OFF_IN1 + 32768, Wtl + OFF_IN1 + 32768, 128,
        b_in1, b_in1 + HID, deg, Ah, Al, N1);
  }
  gconv_hidden(OFF_H1, b_h1, N1);                          // x -> A planes
  gconv_out(Ah, Al, w_out1, b_out1, C0, edges1, E1, N1);   // c1 -> C0
  k_subdiv3<<<(N2 + 255) / 256, 256, 0, stream>>>(C0, edges1, Vv, N1, E1);  // v2
  k_subdiv_feat<<<((size_t)N2 * 32 + 255) / 256, 256, 0, stream>>>(
      Ah, Al, edges1, Dh, Dl, N1, E1);                                      // hs -> D

  // ---------- Stage 2 ----------
  build_csr(edges2, E2, N2);
  k_transpose<<<28 * 28, 128, 0, stream>>>(conv128, T, 28 * 28);
  k_vert_align<<<N2, 128, 0, stream>>>(T, Vv, VAh, VAl, N2, 28, 28);
  k_gather<128><<<((size_t)N2 * 16 + 255) / 256, 256, 0, stream>>>(
      rowptr, adj, VAh, VAl, Gh, Gl, N2);
  k_gather<256><<<((size_t)N2 * 32 + 255) / 256, 256, 0, stream>>>(
      rowptr, adj, Dh, Dl, Bh, Bl, N2);
  {
    const size_t m0 = OFF_IN2, m1 = OFF_IN2 + (size_t)256 * 384;
    Panels pd = {{VAh, Dh, Gh, Bh}, {VAl, Dl, Gl, Bl},
                 {0, 128, 384, 512}, {128, 256, 128, 256}};
    k_layer<<<layerGrid(N2), 256, 0, stream>>>(pd, 768,
        Wth + m0, Wtl + m0, Wth + m1, Wtl + m1, 384,
        b_in2, b_in2 + HID, deg, Ah, Al, N2);
  }
  gconv_hidden(OFF_H2, b_h2, N2);                          // x -> A planes
  gconv_out(Ah, Al, w_out2, b_out2, C0, edges2, E2, N2);   // c2 -> C0
  k_subdiv3<<<(N3 + 255) / 256, 256, 0, stream>>>(C0, edges2, Vv, N2, E2);  // v3
  k_subdiv_feat<<<((size_t)N3 * 32 + 255) / 256, 256, 0, stream>>>(
      Ah, Al, edges2, Dh, Dl, N2, E2);                                      // hs -> D

  // ---------- Stage 3 ----------
  build_csr(edges3, E3, N3);
  k_transpose<<<14 * 14, 128, 0, stream>>>(conv256, T, 14 * 14);
  k_vert_align<<<N3, 128, 0, stream>>>(T, Vv, VAh, VAl, N3, 14, 14);
  k_gather<128><<<((size_t)N3 * 16 + 255) / 256, 256, 0, stream>>>(
      rowptr, adj, VAh, VAl, Gh, Gl, N3);
  k_gather<256><<<((size_t)N3 * 32 + 255) / 256, 256, 0, stream>>>(
      rowptr, adj, Dh, Dl, Bh, Bl, N3);
  {
    const size_t m0 = OFF_IN3, m1 = OFF_IN3 + (size_t)256 * 384;
    Panels pd = {{VAh, Dh, Gh, Bh}, {VAl, Dl, Gl, Bl},
                 {0, 128, 384, 512}, {128, 256, 128, 256}};
    k_layer<<<layerGrid(N3), 256, 0, stream>>>(pd, 768,
        Wth + m0, Wtl + m0, Wth + m1, Wtl + m1, 384,
        b_in3, b_in3 + HID, deg, Ah, Al, N3);
  }
  gconv_hidden(OFF_H3, b_h3, N3);                          // x -> A planes
  float* OUT = (float*)d_out;
  k_rowdot6<<<((size_t)N3 * 64 + 255) / 256, 256, 0, stream>>>(
      Ah, Al, w_out3, b_out3, OUT, C2, N3);
  k_scatter3<<<(E3 + 255) / 256, 256, 0, stream>>>(edges3, C2, OUT, E3);
}